// Round 4
// baseline (304.769 us; speedup 1.0000x reference)
//
#include <hip/hip_runtime.h>
#include <math.h>
#include <stdint.h>

// ---------------------------------------------------------------------------
//   N=50000 nodes, E=400000 edges (+N self loops), EL=100000 label pairs
//   H=8 heads, IN=128, HID=32, OUT=32  -> 256 value cols + 16 logit cols = 272
// ---------------------------------------------------------------------------

typedef __attribute__((ext_vector_type(8))) short bf16x8;   // 8 bf16 = 4 VGPR
typedef __attribute__((ext_vector_type(4))) float f32x4;

__device__ __forceinline__ short bf16_rn(float x) {
  uint32_t u = __float_as_uint(x);
  uint32_t r = (u + 0x7FFFu + ((u >> 16) & 1u)) >> 16;
  return (short)r;
}
__device__ __forceinline__ float bf16_f(short h) {
  return __uint_as_float(((uint32_t)(uint16_t)h) << 16);
}

// ==== W pack: [K][256] f32 (+att vecs) -> [K/8][272][8] bf16 hi/lo =========
// cols 0..255 = W; 256..263 = WS (aS weights); 264..271 = WD.
// WS[k][h] = sum_c W[k][h*32+c] * attS[h][c]  (logits are linear in X).
__global__ __launch_bounds__(320) void wtrans(
    const float* __restrict__ W, const float* __restrict__ attS,
    const float* __restrict__ attD, short* __restrict__ Whi,
    short* __restrict__ Wlo)
{
  const int col = threadIdx.x;
  if (col >= 272) return;
  const int chunk = blockIdx.x;
  float w[8];
  if (col < 256) {
    #pragma unroll
    for (int e = 0; e < 8; ++e)
      w[e] = W[(size_t)(chunk * 8 + e) * 256 + col];
  } else {
    const int h = (col - 256) & 7;
    const float* att = (col < 264) ? attS : attD;
    #pragma unroll
    for (int e = 0; e < 8; ++e) {
      float s = 0.f;
      for (int c = 0; c < 32; ++c)
        s += W[(size_t)(chunk * 8 + e) * 256 + h * 32 + c] * att[h * 32 + c];
      w[e] = s;
    }
  }
  bf16x8 vh, vl;
  #pragma unroll
  for (int e = 0; e < 8; ++e) {
    const short h = bf16_rn(w[e]);
    vh[e] = h;
    vl[e] = bf16_rn(w[e] - bf16_f(h));
  }
  *(bf16x8*)(Whi + ((size_t)chunk * 272 + col) * 8) = vh;
  *(bf16x8*)(Wlo + ((size_t)chunk * 272 + col) * 8) = vl;
}

// ============== split-bf16 MFMA GEMM, swapped operands =====================
// Computes [xh | aS | aD] = X @ Wpacked via 3-pass split-bf16 16x16x32 MFMA.
// Operands SWAPPED: mfma(Wfrag, Xfrag, acc) -> lane holds 4 consecutive COLS
// of row (lane&15): acc[nt][reg] = C[r0+lr][nt*16 + lg*4 + reg] -> f32x4 store.
template<int K>
__global__ __launch_bounds__(256) void mfma_gemm_att(
    const float* __restrict__ X, const short* __restrict__ Whi,
    const short* __restrict__ Wlo, float* __restrict__ xh,
    float* __restrict__ aS, float* __restrict__ aD, int n)
{
  const int lane = threadIdx.x & 63;
  const int wid  = threadIdx.x >> 6;
  const int lr   = lane & 15;
  const int lg   = lane >> 4;
  const int r0   = (blockIdx.x * 4 + wid) * 16;
  if (r0 >= n) return;

  f32x4 acc[17];
  #pragma unroll
  for (int i = 0; i < 17; ++i) acc[i] = (f32x4){0.f, 0.f, 0.f, 0.f};

  const int arow = r0 + lr;
  const bool aok = arow < n;
  const float* xp = X + (size_t)arow * K;

  #pragma unroll
  for (int kc = 0; kc < K / 32; ++kc) {
    float a[8];
    if (aok) {
      const float4 p0 = *(const float4*)(xp + kc * 32 + lg * 8);
      const float4 p1 = *(const float4*)(xp + kc * 32 + lg * 8 + 4);
      a[0] = p0.x; a[1] = p0.y; a[2] = p0.z; a[3] = p0.w;
      a[4] = p1.x; a[5] = p1.y; a[6] = p1.z; a[7] = p1.w;
    } else {
      #pragma unroll
      for (int e = 0; e < 8; ++e) a[e] = 0.f;
    }
    bf16x8 Ah, Al;
    #pragma unroll
    for (int e = 0; e < 8; ++e) {
      const short h = bf16_rn(a[e]);
      Ah[e] = h;
      Al[e] = bf16_rn(a[e] - bf16_f(h));
    }
    const bf16x8* bh = (const bf16x8*)Whi + (size_t)(kc * 4 + lg) * 272;
    const bf16x8* bl = (const bf16x8*)Wlo + (size_t)(kc * 4 + lg) * 272;
    #pragma unroll
    for (int nt = 0; nt < 17; ++nt) {
      const bf16x8 Bh = bh[nt * 16 + lr];
      const bf16x8 Bl = bl[nt * 16 + lr];
      acc[nt] = __builtin_amdgcn_mfma_f32_16x16x32_bf16(Bh, Ah, acc[nt], 0, 0, 0);
      acc[nt] = __builtin_amdgcn_mfma_f32_16x16x32_bf16(Bh, Al, acc[nt], 0, 0, 0);
      acc[nt] = __builtin_amdgcn_mfma_f32_16x16x32_bf16(Bl, Ah, acc[nt], 0, 0, 0);
    }
  }

  const int orow = r0 + lr;
  if (orow < n) {
    float* xo = xh + (size_t)orow * 256;
    #pragma unroll
    for (int nt = 0; nt < 16; ++nt)
      *(f32x4*)(xo + nt * 16 + lg * 4) = acc[nt];
    // logits tile: cols 256+lg*4+reg
    if (lg == 0) *(f32x4*)(aS + (size_t)orow * 8)     = acc[16];
    if (lg == 1) *(f32x4*)(aS + (size_t)orow * 8 + 4) = acc[16];
    if (lg == 2) *(f32x4*)(aD + (size_t)orow * 8)     = acc[16];
    if (lg == 3) *(f32x4*)(aD + (size_t)orow * 8 + 4) = acc[16];
  }
}

// ============================ CSR construction =============================
__global__ void count_kernel(const int* __restrict__ ei, int* __restrict__ deg,
                             int E_, int n) {
  const int i = blockIdx.x * blockDim.x + threadIdx.x;
  const int Et = E_ + n;
  if (i >= Et) return;
  const int dst = (i < E_) ? ei[E_ + i] : (i - E_);
  atomicAdd(&deg[dst], 1);
}

__global__ __launch_bounds__(256) void scan_part(const int* __restrict__ deg,
                                                 int* __restrict__ part, int n) {
  __shared__ int red[256];
  const int tid = threadIdx.x;
  int s = 0;
  #pragma unroll
  for (int j = 0; j < 8; ++j) {
    const int idx = blockIdx.x * 2048 + j * 256 + tid;
    if (idx < n) s += deg[idx];
  }
  red[tid] = s;
  __syncthreads();
  for (int o = 128; o > 0; o >>= 1) {
    if (tid < o) red[tid] += red[tid + o];
    __syncthreads();
  }
  if (tid == 0) part[blockIdx.x] = red[0];
}

__global__ __launch_bounds__(256) void scan_fin(
    const int* __restrict__ deg, const int* __restrict__ part,
    int* __restrict__ off, int* __restrict__ cursor, int n, int nblk) {
  __shared__ int sd[256];
  __shared__ int s_pref;
  const int tid = threadIdx.x;
  if (tid == 0) {
    int p = 0;
    for (int i = 0; i < blockIdx.x; ++i) p += part[i];
    s_pref = p;
  }
  const int base = blockIdx.x * 2048 + tid * 8;
  int v[8];
  int tsum = 0;
  #pragma unroll
  for (int j = 0; j < 8; ++j) {
    const int idx = base + j;
    v[j] = (idx < n) ? deg[idx] : 0;
    tsum += v[j];
  }
  sd[tid] = tsum;
  __syncthreads();
  for (int o = 1; o < 256; o <<= 1) {
    const int t = (tid >= o) ? sd[tid - o] : 0;
    __syncthreads();
    sd[tid] += t;
    __syncthreads();
  }
  int start = s_pref + sd[tid] - tsum;
  #pragma unroll
  for (int j = 0; j < 8; ++j) {
    const int idx = base + j;
    if (idx < n) { off[idx] = start; cursor[idx] = start; }
    start += v[j];
  }
}

__global__ void scatter_kernel(const int* __restrict__ ei, int* __restrict__ cursor,
                               int* __restrict__ csr_src, int E_, int n) {
  const int i = blockIdx.x * blockDim.x + threadIdx.x;
  const int Et = E_ + n;
  if (i >= Et) return;
  int src, dst;
  if (i < E_) { src = ei[i]; dst = ei[E_ + i]; }
  else        { src = i - E_; dst = i - E_; }
  const int pos = atomicAdd(&cursor[dst], 1);
  csr_src[pos] = src;
}

// ===================== per-destination gather + softmax ====================
// 2 waves per node: wave-half w owns heads w*4..w*4+3 (128 channels);
// lane owns 2 channels (float2). Cross-wave head-mean combined via LDS.
template<bool RELU>
__global__ __launch_bounds__(256) void gat_gather(
    const float* __restrict__ xh, const float* __restrict__ aS,
    const float* __restrict__ aD, const int* __restrict__ off,
    const int* __restrict__ deg, const int* __restrict__ csr_src,
    const float* __restrict__ bias, float* __restrict__ out, int n)
{
  __shared__ float red[2][32];
  const int tid  = threadIdx.x;
  const int wave = tid >> 6;
  const int lane = tid & 63;
  const int slot = wave >> 1;       // node slot in block (0/1)
  const int w    = wave & 1;        // half: heads w*4..w*4+3
  const int node = blockIdx.x * 2 + slot;

  int o = 0, d = 0;
  float adst = 0.f;
  const int h = w * 4 + (lane >> 4);
  if (node < n) {
    o = off[node];
    d = deg[node];
    adst = aD[(size_t)node * 8 + h];
  }

  const float2* x2 = (const float2*)xh;
  const size_t cofs = (size_t)w * 64 + lane;   // float2 index within row
  float s = 0.f;
  float2 acc = make_float2(0.f, 0.f);

  int j = 0;
  for (; j + 8 <= d; j += 8) {
    int si[8];
    #pragma unroll
    for (int q = 0; q < 8; ++q) si[q] = csr_src[o + j + q];
    float av[8]; float2 xv[8];
    #pragma unroll
    for (int q = 0; q < 8; ++q) {
      av[q] = aS[(size_t)si[q] * 8 + h];
      xv[q] = x2[(size_t)si[q] * 128 + cofs];
    }
    #pragma unroll
    for (int q = 0; q < 8; ++q) {
      float e = av[q] + adst;
      e = (e > 0.f) ? e : 0.2f * e;
      const float p = __expf(e);
      s += p;
      acc.x += p * xv[q].x;
      acc.y += p * xv[q].y;
    }
  }
  if (j + 4 <= d) {
    int si[4];
    #pragma unroll
    for (int q = 0; q < 4; ++q) si[q] = csr_src[o + j + q];
    float av[4]; float2 xv[4];
    #pragma unroll
    for (int q = 0; q < 4; ++q) {
      av[q] = aS[(size_t)si[q] * 8 + h];
      xv[q] = x2[(size_t)si[q] * 128 + cofs];
    }
    #pragma unroll
    for (int q = 0; q < 4; ++q) {
      float e = av[q] + adst;
      e = (e > 0.f) ? e : 0.2f * e;
      const float p = __expf(e);
      s += p;
      acc.x += p * xv[q].x;
      acc.y += p * xv[q].y;
    }
    j += 4;
  }
  for (; j < d; ++j) {
    const int s0 = csr_src[o + j];
    float e0 = aS[(size_t)s0 * 8 + h] + adst;
    e0 = (e0 > 0.f) ? e0 : 0.2f * e0;
    const float p0 = __expf(e0);
    const float2 x0 = x2[(size_t)s0 * 128 + cofs];
    s += p0;
    acc.x += p0 * x0.x;
    acc.y += p0 * x0.y;
  }

  if (d > 0) {
    const float inv = 1.f / s;
    acc.x *= inv; acc.y *= inv;
  }

  // sum this wave's 4 heads: lanes differing in bits 4,5 share c
  acc.x += __shfl_xor(acc.x, 16); acc.y += __shfl_xor(acc.y, 16);
  acc.x += __shfl_xor(acc.x, 32); acc.y += __shfl_xor(acc.y, 32);

  if (w == 1 && lane < 16) {
    red[slot][lane * 2]     = acc.x;
    red[slot][lane * 2 + 1] = acc.y;
  }
  __syncthreads();
  if (w == 0 && lane < 16 && node < n) {
    const float2 b2 = ((const float2*)bias)[lane];
    float ox = (acc.x + red[slot][lane * 2])     * 0.125f + b2.x;
    float oy = (acc.y + red[slot][lane * 2 + 1]) * 0.125f + b2.y;
    if (RELU) { ox = fmaxf(ox, 0.f); oy = fmaxf(oy, 0.f); }
    *(float2*)(out + (size_t)node * 32 + lane * 2) = make_float2(ox, oy);
  }
}

// ================================ decoder ==================================
__global__ __launch_bounds__(256) void decode_kernel(
    const float* __restrict__ z, const int* __restrict__ eli,
    float* __restrict__ out, int el)
{
  const int t = blockIdx.x * blockDim.x + threadIdx.x;
  const int pair = t >> 3;
  const int sub  = t & 7;
  if (pair >= el) return;
  const int a = eli[pair];
  const int b = eli[el + pair];
  const float4* z4 = reinterpret_cast<const float4*>(z);
  const float4 va = z4[(size_t)a * 8 + sub];
  const float4 vb = z4[(size_t)b * 8 + sub];
  float dp = va.x * vb.x + va.y * vb.y + va.z * vb.z + va.w * vb.w;
  dp += __shfl_xor(dp, 1);
  dp += __shfl_xor(dp, 2);
  dp += __shfl_xor(dp, 4);
  if (sub == 0) out[pair] = dp;
}

// ================================ launcher =================================
extern "C" void kernel_launch(void* const* d_in, const int* in_sizes, int n_in,
                              void* d_out, int out_size, void* d_ws, size_t ws_size,
                              hipStream_t stream)
{
  const float* x   = (const float*)d_in[0];
  const int*   ei  = (const int*)  d_in[1];
  const int*   eli = (const int*)  d_in[2];
  const float* W1  = (const float*)d_in[3];
  const float* as1 = (const float*)d_in[4];
  const float* ad1 = (const float*)d_in[5];
  const float* b1  = (const float*)d_in[6];
  const float* W2  = (const float*)d_in[7];
  const float* as2 = (const float*)d_in[8];
  const float* ad2 = (const float*)d_in[9];
  const float* b2  = (const float*)d_in[10];
  float* out = (float*)d_out;

  const int n  = in_sizes[0] / 128;   // 50000
  const int e  = in_sizes[1] / 2;     // 400000
  const int el = in_sizes[2] / 2;     // 100000
  const int et = e + n;

  // workspace carve-up (16B-aligned chunks)
  char* p = (char*)d_ws;
  float* xh      = (float*)p; p += (size_t)n * 256 * 4;  // 51.2 MB
  float* aS      = (float*)p; p += (size_t)n * 8 * 4;
  float* aD      = (float*)p; p += (size_t)n * 8 * 4;
  int*   deg     = (int*)  p; p += (size_t)n * 4;
  int*   off     = (int*)  p; p += (size_t)n * 4;
  int*   cursor  = (int*)  p; p += (size_t)n * 4;
  int*   part    = (int*)  p; p += 128 * 4;
  int*   csr_src = (int*)  p; p += (size_t)et * 4;
  float* h1      = (float*)p; p += (size_t)n * 32 * 4;
  float* z       = (float*)p; p += (size_t)n * 32 * 4;
  short* W1hi    = (short*)p; p += (size_t)16 * 272 * 8 * 2;
  short* W1lo    = (short*)p; p += (size_t)16 * 272 * 8 * 2;
  short* W2hi    = (short*)p; p += (size_t)4 * 272 * 8 * 2;
  short* W2lo    = (short*)p; p += (size_t)4 * 272 * 8 * 2;

  const int nblk = (n + 2047) / 2048;
  const int gblk = (n + 63) / 64;     // mfma gemm: 4 waves x 16 rows

  hipMemsetAsync(deg, 0, (size_t)n * 4, stream);

  // CSR build + W packs
  count_kernel<<<(et + 255) / 256, 256, 0, stream>>>(ei, deg, e, n);
  scan_part<<<nblk, 256, 0, stream>>>(deg, part, n);
  scan_fin<<<nblk, 256, 0, stream>>>(deg, part, off, cursor, n, nblk);
  scatter_kernel<<<(et + 255) / 256, 256, 0, stream>>>(ei, cursor, csr_src, e, n);
  wtrans<<<16, 320, 0, stream>>>(W1, as1, ad1, W1hi, W1lo);
  wtrans<<<4, 320, 0, stream>>>(W2, as2, ad2, W2hi, W2lo);

  // layer 1
  mfma_gemm_att<128><<<gblk, 256, 0, stream>>>(x, W1hi, W1lo, xh, aS, aD, n);
  gat_gather<true><<<(n + 1) / 2, 256, 0, stream>>>(xh, aS, aD, off, deg, csr_src,
                                                    b1, h1, n);
  // layer 2
  mfma_gemm_att<32><<<gblk, 256, 0, stream>>>(h1, W2hi, W2lo, xh, aS, aD, n);
  gat_gather<false><<<(n + 1) / 2, 256, 0, stream>>>(xh, aS, aD, off, deg, csr_src,
                                                     b2, z, n);
  // decoder
  decode_kernel<<<(el * 8 + 255) / 256, 256, 0, stream>>>(z, eli, out, el);
}

// Round 5
// 279.710 us; speedup vs baseline: 1.0896x; 1.0896x over previous
//
#include <hip/hip_runtime.h>
#include <math.h>
#include <stdint.h>

// ---------------------------------------------------------------------------
//   N=50000 nodes, E=400000 edges (+N self loops), EL=100000 label pairs
//   H=8 heads, IN=128, HID=32, OUT=32  -> 256 value cols + 16 logit cols = 272
// ---------------------------------------------------------------------------

typedef __attribute__((ext_vector_type(8))) short bf16x8;   // 8 bf16 = 4 VGPR
typedef __attribute__((ext_vector_type(4))) float f32x4;

__device__ __forceinline__ short bf16_rn(float x) {
  uint32_t u = __float_as_uint(x);
  uint32_t r = (u + 0x7FFFu + ((u >> 16) & 1u)) >> 16;
  return (short)r;
}
__device__ __forceinline__ float bf16_f(short h) {
  return __uint_as_float(((uint32_t)(uint16_t)h) << 16);
}

// ==== W pack: [K][256] f32 (+att vecs) -> [K/8][272][8] bf16 hi/lo =========
// cols 0..255 = W; 256..263 = WS (aS weights); 264..271 = WD.
// WS[k][h] = sum_c W[k][h*32+c] * attS[h][c]  (logits are linear in X).
__device__ __forceinline__ void wtrans_body(
    const float* __restrict__ W, const float* __restrict__ attS,
    const float* __restrict__ attD, short* __restrict__ Whi,
    short* __restrict__ Wlo, int chunk)
{
  const int col = threadIdx.x;
  if (col >= 272) return;
  float w[8];
  if (col < 256) {
    #pragma unroll
    for (int e = 0; e < 8; ++e)
      w[e] = W[(size_t)(chunk * 8 + e) * 256 + col];
  } else {
    const int h = (col - 256) & 7;
    const float* att = (col < 264) ? attS : attD;
    #pragma unroll
    for (int e = 0; e < 8; ++e) {
      float s = 0.f;
      for (int c = 0; c < 32; ++c)
        s += W[(size_t)(chunk * 8 + e) * 256 + h * 32 + c] * att[h * 32 + c];
      w[e] = s;
    }
  }
  bf16x8 vh, vl;
  #pragma unroll
  for (int e = 0; e < 8; ++e) {
    const short h = bf16_rn(w[e]);
    vh[e] = h;
    vl[e] = bf16_rn(w[e] - bf16_f(h));
  }
  *(bf16x8*)(Whi + ((size_t)chunk * 272 + col) * 8) = vh;
  *(bf16x8*)(Wlo + ((size_t)chunk * 272 + col) * 8) = vl;
}

// fused: blocks 0..15 -> W1 (K=128), blocks 16..19 -> W2 (K=32)
__global__ __launch_bounds__(320) void wtrans_both(
    const float* __restrict__ W1, const float* __restrict__ as1,
    const float* __restrict__ ad1, short* __restrict__ W1hi,
    short* __restrict__ W1lo,
    const float* __restrict__ W2, const float* __restrict__ as2,
    const float* __restrict__ ad2, short* __restrict__ W2hi,
    short* __restrict__ W2lo)
{
  if (blockIdx.x < 16)
    wtrans_body(W1, as1, ad1, W1hi, W1lo, blockIdx.x);
  else
    wtrans_body(W2, as2, ad2, W2hi, W2lo, blockIdx.x - 16);
}

// ============== split-bf16 MFMA GEMM, swapped operands, nt-outer ===========
// [xh | aS | aD] = X @ Wpacked via 3-pass split-bf16 16x16x32 MFMA.
// mfma(Wfrag, Xfrag, acc) -> lane holds 4 consecutive COLS of row (lane&15):
// acc[nt][reg] = C[r0+lr][nt*16 + lg*4 + reg]  -> f32x4 vector store.
// A (X rows) kept in registers across all 17 column tiles.
template<int K>
__global__ __launch_bounds__(256) void mfma_gemm_att(
    const float* __restrict__ X, const short* __restrict__ Whi,
    const short* __restrict__ Wlo, float* __restrict__ xh,
    float* __restrict__ aS, float* __restrict__ aD, int n)
{
  constexpr int KC = K / 32;
  const int lane = threadIdx.x & 63;
  const int wid  = threadIdx.x >> 6;
  const int lr   = lane & 15;
  const int lg   = lane >> 4;
  const int r0   = (blockIdx.x * 4 + wid) * 16;
  if (r0 >= n) return;

  const int arow = r0 + lr;
  const bool aok = arow < n;
  const float* xp = X + (size_t)arow * K;

  // load + split-convert all A fragments once
  bf16x8 Ah[KC], Al[KC];
  #pragma unroll
  for (int kc = 0; kc < KC; ++kc) {
    float a[8];
    if (aok) {
      const float4 p0 = *(const float4*)(xp + kc * 32 + lg * 8);
      const float4 p1 = *(const float4*)(xp + kc * 32 + lg * 8 + 4);
      a[0] = p0.x; a[1] = p0.y; a[2] = p0.z; a[3] = p0.w;
      a[4] = p1.x; a[5] = p1.y; a[6] = p1.z; a[7] = p1.w;
    } else {
      #pragma unroll
      for (int e = 0; e < 8; ++e) a[e] = 0.f;
    }
    #pragma unroll
    for (int e = 0; e < 8; ++e) {
      const short hh = bf16_rn(a[e]);
      Ah[kc][e] = hh;
      Al[kc][e] = bf16_rn(a[e] - bf16_f(hh));
    }
  }

  f32x4 acc[17];
  #pragma unroll
  for (int i = 0; i < 17; ++i) acc[i] = (f32x4){0.f, 0.f, 0.f, 0.f};

  const bf16x8* WH = (const bf16x8*)Whi;
  const bf16x8* WL = (const bf16x8*)Wlo;

  #pragma unroll
  for (int nt = 0; nt < 17; ++nt) {
    #pragma unroll
    for (int kc = 0; kc < KC; ++kc) {
      const size_t bidx = (size_t)(kc * 4 + lg) * 272 + nt * 16 + lr;
      const bf16x8 Bh = WH[bidx];
      const bf16x8 Bl = WL[bidx];
      acc[nt] = __builtin_amdgcn_mfma_f32_16x16x32_bf16(Bh, Ah[kc], acc[nt], 0, 0, 0);
      acc[nt] = __builtin_amdgcn_mfma_f32_16x16x32_bf16(Bh, Al[kc], acc[nt], 0, 0, 0);
      acc[nt] = __builtin_amdgcn_mfma_f32_16x16x32_bf16(Bl, Ah[kc], acc[nt], 0, 0, 0);
    }
  }

  const int orow = r0 + lr;
  if (orow < n) {
    float* xo = xh + (size_t)orow * 256;
    #pragma unroll
    for (int nt = 0; nt < 16; ++nt)
      *(f32x4*)(xo + nt * 16 + lg * 4) = acc[nt];
    if (lg == 0) *(f32x4*)(aS + (size_t)orow * 8)     = acc[16];
    if (lg == 1) *(f32x4*)(aS + (size_t)orow * 8 + 4) = acc[16];
    if (lg == 2) *(f32x4*)(aD + (size_t)orow * 8)     = acc[16];
    if (lg == 3) *(f32x4*)(aD + (size_t)orow * 8 + 4) = acc[16];
  }
}

// ============================ CSR construction =============================
__global__ void count_kernel(const int* __restrict__ ei, int* __restrict__ deg,
                             int E_, int n) {
  const int i = blockIdx.x * blockDim.x + threadIdx.x;
  const int Et = E_ + n;
  if (i >= Et) return;
  const int dst = (i < E_) ? ei[E_ + i] : (i - E_);
  atomicAdd(&deg[dst], 1);
}

__global__ __launch_bounds__(256) void scan_part(const int* __restrict__ deg,
                                                 int* __restrict__ part, int n) {
  __shared__ int red[256];
  const int tid = threadIdx.x;
  int s = 0;
  #pragma unroll
  for (int j = 0; j < 8; ++j) {
    const int idx = blockIdx.x * 2048 + j * 256 + tid;
    if (idx < n) s += deg[idx];
  }
  red[tid] = s;
  __syncthreads();
  for (int o = 128; o > 0; o >>= 1) {
    if (tid < o) red[tid] += red[tid + o];
    __syncthreads();
  }
  if (tid == 0) part[blockIdx.x] = red[0];
}

__global__ __launch_bounds__(256) void scan_fin(
    const int* __restrict__ deg, const int* __restrict__ part,
    int* __restrict__ off, int* __restrict__ cursor, int n, int nblk) {
  __shared__ int sd[256];
  __shared__ int s_pref;
  const int tid = threadIdx.x;
  if (tid == 0) {
    int p = 0;
    for (int i = 0; i < blockIdx.x; ++i) p += part[i];
    s_pref = p;
  }
  const int base = blockIdx.x * 2048 + tid * 8;
  int v[8];
  int tsum = 0;
  #pragma unroll
  for (int j = 0; j < 8; ++j) {
    const int idx = base + j;
    v[j] = (idx < n) ? deg[idx] : 0;
    tsum += v[j];
  }
  sd[tid] = tsum;
  __syncthreads();
  for (int o = 1; o < 256; o <<= 1) {
    const int t = (tid >= o) ? sd[tid - o] : 0;
    __syncthreads();
    sd[tid] += t;
    __syncthreads();
  }
  int start = s_pref + sd[tid] - tsum;
  #pragma unroll
  for (int j = 0; j < 8; ++j) {
    const int idx = base + j;
    if (idx < n) { off[idx] = start; cursor[idx] = start; }
    start += v[j];
  }
}

__global__ void scatter_kernel(const int* __restrict__ ei, int* __restrict__ cursor,
                               int* __restrict__ csr_src, int E_, int n) {
  const int i = blockIdx.x * blockDim.x + threadIdx.x;
  const int Et = E_ + n;
  if (i >= Et) return;
  int src, dst;
  if (i < E_) { src = ei[i]; dst = ei[E_ + i]; }
  else        { src = i - E_; dst = i - E_; }
  const int pos = atomicAdd(&cursor[dst], 1);
  csr_src[pos] = src;
}

// ===================== per-destination gather + softmax ====================
// One wave per node (float4/lane), 2-wave blocks. Double-buffered prefetch:
// batch j+4's csr/aS/xh loads are issued before computing batch j.
template<bool RELU>
__global__ __launch_bounds__(128) void gat_gather(
    const float* __restrict__ xh, const float* __restrict__ aS,
    const float* __restrict__ aD, const int* __restrict__ off,
    const int* __restrict__ deg, const int* __restrict__ csr_src,
    const float* __restrict__ bias, float* __restrict__ out, int n)
{
  const int wid  = threadIdx.x >> 6;
  const int lane = threadIdx.x & 63;
  const int node = blockIdx.x * 2 + wid;
  if (node >= n) return;

  const int h = lane >> 3;
  const float adst = aD[(size_t)node * 8 + h];
  const int o = off[node];
  const int d = deg[node];          // >= 1 (self loop)

  float s = 0.f;
  float4 acc = make_float4(0.f, 0.f, 0.f, 0.f);
  const float4* xh4 = reinterpret_cast<const float4*>(xh);

  int si[4]; float av[4]; float4 xv[4];
  #pragma unroll
  for (int q = 0; q < 4; ++q) {
    const int jj = (q < d) ? q : (d - 1);
    si[q] = csr_src[o + jj];
  }
  #pragma unroll
  for (int q = 0; q < 4; ++q) av[q] = aS[(size_t)si[q] * 8 + h];
  #pragma unroll
  for (int q = 0; q < 4; ++q) xv[q] = xh4[(size_t)si[q] * 64 + lane];

  for (int j = 0; j < d; j += 4) {
    const bool more = (j + 4) < d;
    int nsi[4]; float nav[4]; float4 nxv[4];
    if (more) {
      #pragma unroll
      for (int q = 0; q < 4; ++q) {
        int jj = j + 4 + q;
        jj = (jj < d) ? jj : (d - 1);
        nsi[q] = csr_src[o + jj];
      }
      #pragma unroll
      for (int q = 0; q < 4; ++q) nav[q] = aS[(size_t)nsi[q] * 8 + h];
      #pragma unroll
      for (int q = 0; q < 4; ++q) nxv[q] = xh4[(size_t)nsi[q] * 64 + lane];
    }
    #pragma unroll
    for (int q = 0; q < 4; ++q) {
      float e = av[q] + adst;
      e = (e > 0.f) ? e : 0.2f * e;
      float p = __expf(e);
      if (j + q >= d) p = 0.f;
      s += p;
      acc.x += p * xv[q].x;
      acc.y += p * xv[q].y;
      acc.z += p * xv[q].z;
      acc.w += p * xv[q].w;
    }
    if (more) {
      #pragma unroll
      for (int q = 0; q < 4; ++q) { si[q] = nsi[q]; av[q] = nav[q]; xv[q] = nxv[q]; }
    }
  }

  const float inv = 1.f / s;
  acc.x *= inv; acc.y *= inv; acc.z *= inv; acc.w *= inv;

  // mean over heads: lanes differing in bits 3..5 share c, different h
  #pragma unroll
  for (int msk = 8; msk <= 32; msk <<= 1) {
    acc.x += __shfl_xor(acc.x, msk);
    acc.y += __shfl_xor(acc.y, msk);
    acc.z += __shfl_xor(acc.z, msk);
    acc.w += __shfl_xor(acc.w, msk);
  }

  if (lane < 8) {
    const float4 b4 = reinterpret_cast<const float4*>(bias)[lane];
    float4 o4;
    o4.x = acc.x * 0.125f + b4.x;
    o4.y = acc.y * 0.125f + b4.y;
    o4.z = acc.z * 0.125f + b4.z;
    o4.w = acc.w * 0.125f + b4.w;
    if (RELU) {
      o4.x = fmaxf(o4.x, 0.f); o4.y = fmaxf(o4.y, 0.f);
      o4.z = fmaxf(o4.z, 0.f); o4.w = fmaxf(o4.w, 0.f);
    }
    reinterpret_cast<float4*>(out + (size_t)node * 32)[lane] = o4;
  }
}

// ================================ decoder ==================================
__global__ __launch_bounds__(256) void decode_kernel(
    const float* __restrict__ z, const int* __restrict__ eli,
    float* __restrict__ out, int el)
{
  const int t = blockIdx.x * blockDim.x + threadIdx.x;
  const int pair = t >> 3;
  const int sub  = t & 7;
  if (pair >= el) return;
  const int a = eli[pair];
  const int b = eli[el + pair];
  const float4* z4 = reinterpret_cast<const float4*>(z);
  const float4 va = z4[(size_t)a * 8 + sub];
  const float4 vb = z4[(size_t)b * 8 + sub];
  float dp = va.x * vb.x + va.y * vb.y + va.z * vb.z + va.w * vb.w;
  dp += __shfl_xor(dp, 1);
  dp += __shfl_xor(dp, 2);
  dp += __shfl_xor(dp, 4);
  if (sub == 0) out[pair] = dp;
}

// ================================ launcher =================================
extern "C" void kernel_launch(void* const* d_in, const int* in_sizes, int n_in,
                              void* d_out, int out_size, void* d_ws, size_t ws_size,
                              hipStream_t stream)
{
  const float* x   = (const float*)d_in[0];
  const int*   ei  = (const int*)  d_in[1];
  const int*   eli = (const int*)  d_in[2];
  const float* W1  = (const float*)d_in[3];
  const float* as1 = (const float*)d_in[4];
  const float* ad1 = (const float*)d_in[5];
  const float* b1  = (const float*)d_in[6];
  const float* W2  = (const float*)d_in[7];
  const float* as2 = (const float*)d_in[8];
  const float* ad2 = (const float*)d_in[9];
  const float* b2  = (const float*)d_in[10];
  float* out = (float*)d_out;

  const int n  = in_sizes[0] / 128;   // 50000
  const int e  = in_sizes[1] / 2;     // 400000
  const int el = in_sizes[2] / 2;     // 100000
  const int et = e + n;

  // workspace carve-up (16B-aligned chunks)
  char* p = (char*)d_ws;
  float* xh      = (float*)p; p += (size_t)n * 256 * 4;  // 51.2 MB
  float* aS      = (float*)p; p += (size_t)n * 8 * 4;
  float* aD      = (float*)p; p += (size_t)n * 8 * 4;
  int*   deg     = (int*)  p; p += (size_t)n * 4;
  int*   off     = (int*)  p; p += (size_t)n * 4;
  int*   cursor  = (int*)  p; p += (size_t)n * 4;
  int*   part    = (int*)  p; p += 128 * 4;
  int*   csr_src = (int*)  p; p += (size_t)et * 4;
  float* h1      = (float*)p; p += (size_t)n * 32 * 4;
  float* z       = (float*)p; p += (size_t)n * 32 * 4;
  short* W1hi    = (short*)p; p += (size_t)16 * 272 * 8 * 2;
  short* W1lo    = (short*)p; p += (size_t)16 * 272 * 8 * 2;
  short* W2hi    = (short*)p; p += (size_t)4 * 272 * 8 * 2;
  short* W2lo    = (short*)p; p += (size_t)4 * 272 * 8 * 2;

  const int nblk = (n + 2047) / 2048;
  const int gblk = (n + 63) / 64;     // mfma gemm: 4 waves x 16 rows

  hipMemsetAsync(deg, 0, (size_t)n * 4, stream);

  // CSR build + fused W packs
  count_kernel<<<(et + 255) / 256, 256, 0, stream>>>(ei, deg, e, n);
  scan_part<<<nblk, 256, 0, stream>>>(deg, part, n);
  scan_fin<<<nblk, 256, 0, stream>>>(deg, part, off, cursor, n, nblk);
  scatter_kernel<<<(et + 255) / 256, 256, 0, stream>>>(ei, cursor, csr_src, e, n);
  wtrans_both<<<20, 320, 0, stream>>>(W1, as1, ad1, W1hi, W1lo,
                                      W2, as2, ad2, W2hi, W2lo);

  // layer 1
  mfma_gemm_att<128><<<gblk, 256, 0, stream>>>(x, W1hi, W1lo, xh, aS, aD, n);
  gat_gather<true><<<(n + 1) / 2, 128, 0, stream>>>(xh, aS, aD, off, deg, csr_src,
                                                    b1, h1, n);
  // layer 2
  mfma_gemm_att<32><<<gblk, 256, 0, stream>>>(h1, W2hi, W2lo, xh, aS, aD, n);
  gat_gather<false><<<(n + 1) / 2, 128, 0, stream>>>(xh, aS, aD, off, deg, csr_src,
                                                     b2, z, n);
  // decoder
  decode_kernel<<<(el * 8 + 255) / 256, 256, 0, stream>>>(z, eli, out, el);
}

// Round 6
// 240.380 us; speedup vs baseline: 1.2679x; 1.1636x over previous
//
#include <hip/hip_runtime.h>
#include <hip/hip_fp16.h>
#include <math.h>
#include <stdint.h>

// ---------------------------------------------------------------------------
//   N=50000 nodes, E=400000 edges (+N self loops), EL=100000 label pairs
//   H=8 heads, IN=128, HID=32, OUT=32  -> 256 value cols + 16 logit cols = 272
//   xh stored FP16 (gather is the sole consumer); logits aS/aD stay FP32.
// ---------------------------------------------------------------------------

typedef __attribute__((ext_vector_type(8))) short bf16x8;   // 8 bf16 = 4 VGPR
typedef __attribute__((ext_vector_type(4))) float f32x4;

__device__ __forceinline__ short bf16_rn(float x) {
  uint32_t u = __float_as_uint(x);
  uint32_t r = (u + 0x7FFFu + ((u >> 16) & 1u)) >> 16;
  return (short)r;
}
__device__ __forceinline__ float bf16_f(short h) {
  return __uint_as_float(((uint32_t)(uint16_t)h) << 16);
}

// ==== W pack: [K][256] f32 (+att vecs) -> [K/8][272][8] bf16 hi/lo =========
// cols 0..255 = W; 256..263 = WS (aS weights); 264..271 = WD.
// WS[k][h] = sum_c W[k][h*32+c] * attS[h][c]  (logits are linear in X).
__device__ __forceinline__ void wtrans_body(
    const float* __restrict__ W, const float* __restrict__ attS,
    const float* __restrict__ attD, short* __restrict__ Whi,
    short* __restrict__ Wlo, int chunk)
{
  const int col = threadIdx.x;
  if (col >= 272) return;
  float w[8];
  if (col < 256) {
    #pragma unroll
    for (int e = 0; e < 8; ++e)
      w[e] = W[(size_t)(chunk * 8 + e) * 256 + col];
  } else {
    const int h = (col - 256) & 7;
    const float* att = (col < 264) ? attS : attD;
    #pragma unroll
    for (int e = 0; e < 8; ++e) {
      float s = 0.f;
      for (int c = 0; c < 32; ++c)
        s += W[(size_t)(chunk * 8 + e) * 256 + h * 32 + c] * att[h * 32 + c];
      w[e] = s;
    }
  }
  bf16x8 vh, vl;
  #pragma unroll
  for (int e = 0; e < 8; ++e) {
    const short h = bf16_rn(w[e]);
    vh[e] = h;
    vl[e] = bf16_rn(w[e] - bf16_f(h));
  }
  *(bf16x8*)(Whi + ((size_t)chunk * 272 + col) * 8) = vh;
  *(bf16x8*)(Wlo + ((size_t)chunk * 272 + col) * 8) = vl;
}

__global__ __launch_bounds__(320) void wtrans_both(
    const float* __restrict__ W1, const float* __restrict__ as1,
    const float* __restrict__ ad1, short* __restrict__ W1hi,
    short* __restrict__ W1lo,
    const float* __restrict__ W2, const float* __restrict__ as2,
    const float* __restrict__ ad2, short* __restrict__ W2hi,
    short* __restrict__ W2lo)
{
  if (blockIdx.x < 16)
    wtrans_body(W1, as1, ad1, W1hi, W1lo, blockIdx.x);
  else
    wtrans_body(W2, as2, ad2, W2hi, W2lo, blockIdx.x - 16);
}

// ============== split-bf16 MFMA GEMM, swapped operands, nt-outer ===========
// [xh(fp16) | aS | aD] = X @ Wpacked via 3-pass split-bf16 16x16x32 MFMA.
// mfma(Wfrag, Xfrag, acc) -> lane holds 4 consecutive COLS of row (lane&15):
// acc[nt][reg] = C[r0+lr][nt*16 + lg*4 + reg].
template<int K>
__global__ __launch_bounds__(256) void mfma_gemm_att(
    const float* __restrict__ X, const short* __restrict__ Whi,
    const short* __restrict__ Wlo, __half* __restrict__ xh,
    float* __restrict__ aS, float* __restrict__ aD, int n)
{
  constexpr int KC = K / 32;
  const int lane = threadIdx.x & 63;
  const int wid  = threadIdx.x >> 6;
  const int lr   = lane & 15;
  const int lg   = lane >> 4;
  const int r0   = (blockIdx.x * 4 + wid) * 16;
  if (r0 >= n) return;

  const int arow = r0 + lr;
  const bool aok = arow < n;
  const float* xp = X + (size_t)arow * K;

  bf16x8 Ah[KC], Al[KC];
  #pragma unroll
  for (int kc = 0; kc < KC; ++kc) {
    float a[8];
    if (aok) {
      const float4 p0 = *(const float4*)(xp + kc * 32 + lg * 8);
      const float4 p1 = *(const float4*)(xp + kc * 32 + lg * 8 + 4);
      a[0] = p0.x; a[1] = p0.y; a[2] = p0.z; a[3] = p0.w;
      a[4] = p1.x; a[5] = p1.y; a[6] = p1.z; a[7] = p1.w;
    } else {
      #pragma unroll
      for (int e = 0; e < 8; ++e) a[e] = 0.f;
    }
    #pragma unroll
    for (int e = 0; e < 8; ++e) {
      const short hh = bf16_rn(a[e]);
      Ah[kc][e] = hh;
      Al[kc][e] = bf16_rn(a[e] - bf16_f(hh));
    }
  }

  f32x4 acc[17];
  #pragma unroll
  for (int i = 0; i < 17; ++i) acc[i] = (f32x4){0.f, 0.f, 0.f, 0.f};

  const bf16x8* WH = (const bf16x8*)Whi;
  const bf16x8* WL = (const bf16x8*)Wlo;

  #pragma unroll
  for (int nt = 0; nt < 17; ++nt) {
    #pragma unroll
    for (int kc = 0; kc < KC; ++kc) {
      const size_t bidx = (size_t)(kc * 4 + lg) * 272 + nt * 16 + lr;
      const bf16x8 Bh = WH[bidx];
      const bf16x8 Bl = WL[bidx];
      acc[nt] = __builtin_amdgcn_mfma_f32_16x16x32_bf16(Bh, Ah[kc], acc[nt], 0, 0, 0);
      acc[nt] = __builtin_amdgcn_mfma_f32_16x16x32_bf16(Bh, Al[kc], acc[nt], 0, 0, 0);
      acc[nt] = __builtin_amdgcn_mfma_f32_16x16x32_bf16(Bl, Ah[kc], acc[nt], 0, 0, 0);
    }
  }

  const int orow = r0 + lr;
  if (orow < n) {
    __half* xo = xh + (size_t)orow * 256;
    #pragma unroll
    for (int nt = 0; nt < 16; ++nt) {
      union { __half2 h[2]; uint2 u; } pk;
      pk.h[0] = __float22half2_rn(make_float2(acc[nt][0], acc[nt][1]));
      pk.h[1] = __float22half2_rn(make_float2(acc[nt][2], acc[nt][3]));
      *(uint2*)(xo + nt * 16 + lg * 4) = pk.u;
    }
    if (lg == 0) *(f32x4*)(aS + (size_t)orow * 8)     = acc[16];
    if (lg == 1) *(f32x4*)(aS + (size_t)orow * 8 + 4) = acc[16];
    if (lg == 2) *(f32x4*)(aD + (size_t)orow * 8)     = acc[16];
    if (lg == 3) *(f32x4*)(aD + (size_t)orow * 8 + 4) = acc[16];
  }
}

// ============================ CSR construction =============================
__global__ void count_kernel(const int* __restrict__ ei, int* __restrict__ deg,
                             int E_, int n) {
  const int i = blockIdx.x * blockDim.x + threadIdx.x;
  const int Et = E_ + n;
  if (i >= Et) return;
  const int dst = (i < E_) ? ei[E_ + i] : (i - E_);
  atomicAdd(&deg[dst], 1);
}

__global__ __launch_bounds__(256) void scan_part(const int* __restrict__ deg,
                                                 int* __restrict__ part, int n) {
  __shared__ int red[256];
  const int tid = threadIdx.x;
  int s = 0;
  #pragma unroll
  for (int j = 0; j < 8; ++j) {
    const int idx = blockIdx.x * 2048 + j * 256 + tid;
    if (idx < n) s += deg[idx];
  }
  red[tid] = s;
  __syncthreads();
  for (int o = 128; o > 0; o >>= 1) {
    if (tid < o) red[tid] += red[tid + o];
    __syncthreads();
  }
  if (tid == 0) part[blockIdx.x] = red[0];
}

__global__ __launch_bounds__(256) void scan_fin(
    const int* __restrict__ deg, const int* __restrict__ part,
    int* __restrict__ off, int* __restrict__ cursor, int n, int nblk) {
  __shared__ int sd[256];
  __shared__ int s_pref;
  const int tid = threadIdx.x;
  if (tid == 0) {
    int p = 0;
    for (int i = 0; i < blockIdx.x; ++i) p += part[i];
    s_pref = p;
  }
  const int base = blockIdx.x * 2048 + tid * 8;
  int v[8];
  int tsum = 0;
  #pragma unroll
  for (int j = 0; j < 8; ++j) {
    const int idx = base + j;
    v[j] = (idx < n) ? deg[idx] : 0;
    tsum += v[j];
  }
  sd[tid] = tsum;
  __syncthreads();
  for (int o = 1; o < 256; o <<= 1) {
    const int t = (tid >= o) ? sd[tid - o] : 0;
    __syncthreads();
    sd[tid] += t;
    __syncthreads();
  }
  int start = s_pref + sd[tid] - tsum;
  #pragma unroll
  for (int j = 0; j < 8; ++j) {
    const int idx = base + j;
    if (idx < n) { off[idx] = start; cursor[idx] = start; }
    start += v[j];
  }
}

__global__ void scatter_kernel(const int* __restrict__ ei, int* __restrict__ cursor,
                               int* __restrict__ csr_src, int E_, int n) {
  const int i = blockIdx.x * blockDim.x + threadIdx.x;
  const int Et = E_ + n;
  if (i >= Et) return;
  int src, dst;
  if (i < E_) { src = ei[i]; dst = ei[E_ + i]; }
  else        { src = i - E_; dst = i - E_; }
  const int pos = atomicAdd(&cursor[dst], 1);
  csr_src[pos] = src;
}

// ===================== per-destination gather + softmax ====================
// One wave per node, fp16 xh. Lane half (bit5) owns edge j / j+1 of each
// pair; sublane (lane&31) owns 8 channels (16B load). Halves merged via
// shfl_xor(32); head-mean via xor 4/8/16. 4-edge unrolled loop, masked tail.
__device__ __forceinline__ void edge_step(
    const __half* __restrict__ xh, const float* __restrict__ aS,
    const int* __restrict__ csr, int o, int d, int jj, int h, int sub,
    float adst, float& s, float* acc)
{
  const bool valid = jj < d;
  const int src = csr[o + (valid ? jj : 0)];
  float e = aS[src * 8 + h] + adst;
  e = (e > 0.f) ? e : 0.2f * e;
  const float p = valid ? __expf(e) : 0.f;
  const float4 raw = *(const float4*)(xh + (size_t)src * 256 + sub * 8);
  const __half2* hp = (const __half2*)&raw;
  float2 f;
  f = __half22float2(hp[0]); acc[0] += p * f.x; acc[1] += p * f.y;
  f = __half22float2(hp[1]); acc[2] += p * f.x; acc[3] += p * f.y;
  f = __half22float2(hp[2]); acc[4] += p * f.x; acc[5] += p * f.y;
  f = __half22float2(hp[3]); acc[6] += p * f.x; acc[7] += p * f.y;
  s += p;
}

template<bool RELU>
__global__ __launch_bounds__(128) void gat_gather(
    const __half* __restrict__ xh, const float* __restrict__ aS,
    const float* __restrict__ aD, const int* __restrict__ off,
    const int* __restrict__ deg, const int* __restrict__ csr_src,
    const float* __restrict__ bias, float* __restrict__ out, int n)
{
  const int wid  = threadIdx.x >> 6;
  const int lane = threadIdx.x & 63;
  const int node = blockIdx.x * 2 + wid;
  if (node >= n) return;

  const int half = lane >> 5;     // edge slot within pair
  const int sub  = lane & 31;     // channels sub*8 .. sub*8+7
  const int h    = sub >> 2;      // head
  const float adst = aD[(size_t)node * 8 + h];
  const int o = off[node];
  const int d = deg[node];        // >= 1 (self loop)

  float s = 0.f;
  float acc[8] = {0.f, 0.f, 0.f, 0.f, 0.f, 0.f, 0.f, 0.f};

  for (int j = 0; j < d; j += 4) {
    edge_step(xh, aS, csr_src, o, d, j + half,     h, sub, adst, s, acc);
    edge_step(xh, aS, csr_src, o, d, j + 2 + half, h, sub, adst, s, acc);
  }

  // merge the two edge-halves (bit 5)
  s += __shfl_xor(s, 32);
  #pragma unroll
  for (int k = 0; k < 8; ++k) acc[k] += __shfl_xor(acc[k], 32);

  const float inv = 1.f / s;      // per-head normalization
  #pragma unroll
  for (int k = 0; k < 8; ++k) acc[k] *= inv;

  // mean over heads: bits 2..4 of sublane index the head
  #pragma unroll
  for (int msk = 4; msk <= 16; msk <<= 1) {
    #pragma unroll
    for (int k = 0; k < 8; ++k) acc[k] += __shfl_xor(acc[k], msk);
  }

  if (lane < 4) {                 // lane owns out channels lane*8..+7
    const float4* b4 = (const float4*)bias;
    const float4 bb0 = b4[lane * 2], bb1 = b4[lane * 2 + 1];
    float4 o0, o1;
    o0.x = acc[0] * 0.125f + bb0.x; o0.y = acc[1] * 0.125f + bb0.y;
    o0.z = acc[2] * 0.125f + bb0.z; o0.w = acc[3] * 0.125f + bb0.w;
    o1.x = acc[4] * 0.125f + bb1.x; o1.y = acc[5] * 0.125f + bb1.y;
    o1.z = acc[6] * 0.125f + bb1.z; o1.w = acc[7] * 0.125f + bb1.w;
    if (RELU) {
      o0.x = fmaxf(o0.x, 0.f); o0.y = fmaxf(o0.y, 0.f);
      o0.z = fmaxf(o0.z, 0.f); o0.w = fmaxf(o0.w, 0.f);
      o1.x = fmaxf(o1.x, 0.f); o1.y = fmaxf(o1.y, 0.f);
      o1.z = fmaxf(o1.z, 0.f); o1.w = fmaxf(o1.w, 0.f);
    }
    float4* op = (float4*)(out + (size_t)node * 32 + lane * 8);
    op[0] = o0; op[1] = o1;
  }
}

// ================================ decoder ==================================
__global__ __launch_bounds__(256) void decode_kernel(
    const float* __restrict__ z, const int* __restrict__ eli,
    float* __restrict__ out, int el)
{
  const int t = blockIdx.x * blockDim.x + threadIdx.x;
  const int pair = t >> 3;
  const int sub  = t & 7;
  if (pair >= el) return;
  const int a = eli[pair];
  const int b = eli[el + pair];
  const float4* z4 = reinterpret_cast<const float4*>(z);
  const float4 va = z4[(size_t)a * 8 + sub];
  const float4 vb = z4[(size_t)b * 8 + sub];
  float dp = va.x * vb.x + va.y * vb.y + va.z * vb.z + va.w * vb.w;
  dp += __shfl_xor(dp, 1);
  dp += __shfl_xor(dp, 2);
  dp += __shfl_xor(dp, 4);
  if (sub == 0) out[pair] = dp;
}

// ================================ launcher =================================
extern "C" void kernel_launch(void* const* d_in, const int* in_sizes, int n_in,
                              void* d_out, int out_size, void* d_ws, size_t ws_size,
                              hipStream_t stream)
{
  const float* x   = (const float*)d_in[0];
  const int*   ei  = (const int*)  d_in[1];
  const int*   eli = (const int*)  d_in[2];
  const float* W1  = (const float*)d_in[3];
  const float* as1 = (const float*)d_in[4];
  const float* ad1 = (const float*)d_in[5];
  const float* b1  = (const float*)d_in[6];
  const float* W2  = (const float*)d_in[7];
  const float* as2 = (const float*)d_in[8];
  const float* ad2 = (const float*)d_in[9];
  const float* b2  = (const float*)d_in[10];
  float* out = (float*)d_out;

  const int n  = in_sizes[0] / 128;   // 50000
  const int e  = in_sizes[1] / 2;     // 400000
  const int el = in_sizes[2] / 2;     // 100000
  const int et = e + n;

  // workspace carve-up (16B-aligned chunks)
  char* p = (char*)d_ws;
  __half* xh     = (__half*)p; p += (size_t)n * 256 * 2;  // 25.6 MB fp16
  float* aS      = (float*)p; p += (size_t)n * 8 * 4;
  float* aD      = (float*)p; p += (size_t)n * 8 * 4;
  int*   deg     = (int*)  p; p += (size_t)n * 4;
  int*   off     = (int*)  p; p += (size_t)n * 4;
  int*   cursor  = (int*)  p; p += (size_t)n * 4;
  int*   part    = (int*)  p; p += 128 * 4;
  int*   csr_src = (int*)  p; p += (size_t)et * 4;
  float* h1      = (float*)p; p += (size_t)n * 32 * 4;
  float* z       = (float*)p; p += (size_t)n * 32 * 4;
  short* W1hi    = (short*)p; p += (size_t)16 * 272 * 8 * 2;
  short* W1lo    = (short*)p; p += (size_t)16 * 272 * 8 * 2;
  short* W2hi    = (short*)p; p += (size_t)4 * 272 * 8 * 2;
  short* W2lo    = (short*)p; p += (size_t)4 * 272 * 8 * 2;

  const int nblk = (n + 2047) / 2048;
  const int gblk = (n + 63) / 64;     // mfma gemm: 4 waves x 16 rows

  hipMemsetAsync(deg, 0, (size_t)n * 4, stream);

  // CSR build + fused W packs
  count_kernel<<<(et + 255) / 256, 256, 0, stream>>>(ei, deg, e, n);
  scan_part<<<nblk, 256, 0, stream>>>(deg, part, n);
  scan_fin<<<nblk, 256, 0, stream>>>(deg, part, off, cursor, n, nblk);
  scatter_kernel<<<(et + 255) / 256, 256, 0, stream>>>(ei, cursor, csr_src, e, n);
  wtrans_both<<<20, 320, 0, stream>>>(W1, as1, ad1, W1hi, W1lo,
                                      W2, as2, ad2, W2hi, W2lo);

  // layer 1
  mfma_gemm_att<128><<<gblk, 256, 0, stream>>>(x, W1hi, W1lo, xh, aS, aD, n);
  gat_gather<true><<<(n + 1) / 2, 128, 0, stream>>>(xh, aS, aD, off, deg, csr_src,
                                                    b1, h1, n);
  // layer 2
  mfma_gemm_att<32><<<gblk, 256, 0, stream>>>(h1, W2hi, W2lo, xh, aS, aD, n);
  gat_gather<false><<<(n + 1) / 2, 128, 0, stream>>>(xh, aS, aD, off, deg, csr_src,
                                                     b2, z, n);
  // decoder
  decode_kernel<<<(el * 8 + 255) / 256, 256, 0, stream>>>(z, eli, out, el);
}

// Round 7
// 211.911 us; speedup vs baseline: 1.4382x; 1.1343x over previous
//
#include <hip/hip_runtime.h>
#include <hip/hip_fp16.h>
#include <math.h>
#include <stdint.h>

// ---------------------------------------------------------------------------
//   N=50000 nodes, E=400000 edges (+N self loops), EL=100000 label pairs
//   H=8 heads, IN=128, HID=32, OUT=32  -> 256 value cols + 16 logit cols = 272
//   xh stored FP16; GEMM runs single-pass fp16 MFMA (error ~ fp16 storage).
// ---------------------------------------------------------------------------

typedef __attribute__((ext_vector_type(8))) _Float16 f16x8;  // 8 f16 = 4 VGPR
typedef __attribute__((ext_vector_type(4))) float f32x4;

// ==== W pack: [K][256] f32 (+att vecs) -> [K/8][272][8] fp16 ===============
// cols 0..255 = W; 256..263 = WS (aS weights); 264..271 = WD.
// WS[k][h] = sum_c W[k][h*32+c] * attS[h][c]  (logits are linear in X).
__device__ __forceinline__ void wtrans_body(
    const float* __restrict__ W, const float* __restrict__ attS,
    const float* __restrict__ attD, _Float16* __restrict__ Wp, int chunk)
{
  const int col = threadIdx.x;
  if (col >= 272) return;
  float w[8];
  if (col < 256) {
    #pragma unroll
    for (int e = 0; e < 8; ++e)
      w[e] = W[(size_t)(chunk * 8 + e) * 256 + col];
  } else {
    const int h = (col - 256) & 7;
    const float* att = (col < 264) ? attS : attD;
    #pragma unroll
    for (int e = 0; e < 8; ++e) {
      float s = 0.f;
      for (int c = 0; c < 32; ++c)
        s += W[(size_t)(chunk * 8 + e) * 256 + h * 32 + c] * att[h * 32 + c];
      w[e] = s;
    }
  }
  f16x8 v;
  #pragma unroll
  for (int e = 0; e < 8; ++e) v[e] = (_Float16)w[e];
  *(f16x8*)(Wp + ((size_t)chunk * 272 + col) * 8) = v;
}

__global__ __launch_bounds__(320) void wtrans_both(
    const float* __restrict__ W1, const float* __restrict__ as1,
    const float* __restrict__ ad1, _Float16* __restrict__ W1p,
    const float* __restrict__ W2, const float* __restrict__ as2,
    const float* __restrict__ ad2, _Float16* __restrict__ W2p)
{
  if (blockIdx.x < 16)
    wtrans_body(W1, as1, ad1, W1p, blockIdx.x);
  else
    wtrans_body(W2, as2, ad2, W2p, blockIdx.x - 16);
}

// ================= fp16 MFMA GEMM, swapped operands ========================
// [xh(fp16) | aS | aD] = X @ Wpacked, single-pass 16x16x32 f16 MFMA.
// mfma(Wfrag, Xfrag, acc): acc[nt][reg] = C[r0+lr][nt*16 + lg*4 + reg].
// kc-outer/nt-inner: 17 independent 4-deep chains (ILP). Epilogue goes
// through per-wave LDS tile for coalesced 1KB fp16 row stores.
template<int K>
__global__ __launch_bounds__(256) void mfma_gemm_att(
    const float* __restrict__ X, const _Float16* __restrict__ Wp,
    __half* __restrict__ xh, float* __restrict__ aS, float* __restrict__ aD,
    int n)
{
  constexpr int KC = K / 32;
  __shared__ _Float16 tile[4][16][264];   // stride 264: 2-way-free ds_write
  const int lane = threadIdx.x & 63;
  const int wid  = threadIdx.x >> 6;
  const int lr   = lane & 15;
  const int lg   = lane >> 4;
  const int r0   = (blockIdx.x * 4 + wid) * 16;
  if (r0 >= n) return;

  const int arow = r0 + lr;
  const bool aok = arow < n;
  const float* xp = X + (size_t)arow * K;

  // A fragments: row lr, k = kc*32 + lg*8 + e, fp16 RN
  f16x8 A[KC];
  #pragma unroll
  for (int kc = 0; kc < KC; ++kc) {
    float a[8];
    if (aok) {
      const float4 p0 = *(const float4*)(xp + kc * 32 + lg * 8);
      const float4 p1 = *(const float4*)(xp + kc * 32 + lg * 8 + 4);
      a[0] = p0.x; a[1] = p0.y; a[2] = p0.z; a[3] = p0.w;
      a[4] = p1.x; a[5] = p1.y; a[6] = p1.z; a[7] = p1.w;
    } else {
      #pragma unroll
      for (int e = 0; e < 8; ++e) a[e] = 0.f;
    }
    #pragma unroll
    for (int e = 0; e < 8; ++e) A[kc][e] = (_Float16)a[e];
  }

  f32x4 acc[17];
  #pragma unroll
  for (int i = 0; i < 17; ++i) acc[i] = (f32x4){0.f, 0.f, 0.f, 0.f};

  const f16x8* WH = (const f16x8*)Wp;
  #pragma unroll
  for (int kc = 0; kc < KC; ++kc) {
    const f16x8* wrow = WH + (size_t)(kc * 4 + lg) * 272;
    #pragma unroll
    for (int nt = 0; nt < 17; ++nt) {
      const f16x8 B = wrow[nt * 16 + lr];
      acc[nt] = __builtin_amdgcn_mfma_f32_16x16x32_f16(B, A[kc], acc[nt], 0, 0, 0);
    }
  }

  // --- logits (cols 256..271) ---
  const int orow = r0 + lr;
  if (orow < n) {
    if (lg == 0) *(f32x4*)(aS + (size_t)orow * 8)     = acc[16];
    if (lg == 1) *(f32x4*)(aS + (size_t)orow * 8 + 4) = acc[16];
    if (lg == 2) *(f32x4*)(aD + (size_t)orow * 8)     = acc[16];
    if (lg == 3) *(f32x4*)(aD + (size_t)orow * 8 + 4) = acc[16];
  }

  // --- xh via LDS: lane writes its 4-col slivers, then coalesced copy ---
  #pragma unroll
  for (int nt = 0; nt < 16; ++nt) {
    _Float16 pk[4];
    #pragma unroll
    for (int j = 0; j < 4; ++j) pk[j] = (_Float16)acc[nt][j];
    *(uint2*)&tile[wid][lr][nt * 16 + lg * 4] = *(uint2*)pk;
  }
  __builtin_amdgcn_s_waitcnt(0);  // drain lgkm before re-reading own tile
  const int crow = lane >> 5;     // 2 rows per pass
  const int cch  = lane & 31;     // 8-half chunk
  #pragma unroll
  for (int ps = 0; ps < 8; ++ps) {
    const int row = ps * 2 + crow;
    const int grow = r0 + row;
    const uint2* src = (const uint2*)&tile[wid][row][cch * 8];
    if (grow < n) {
      uint2 v0 = src[0], v1 = src[1];
      *(uint4*)(xh + (size_t)grow * 256 + cch * 8) =
          make_uint4(v0.x, v0.y, v1.x, v1.y);
    }
  }
}

// ============================ CSR construction =============================
__global__ void count_kernel(const int* __restrict__ ei, int* __restrict__ deg,
                             int E_, int n) {
  const int i = blockIdx.x * blockDim.x + threadIdx.x;
  const int Et = E_ + n;
  if (i >= Et) return;
  const int dst = (i < E_) ? ei[E_ + i] : (i - E_);
  atomicAdd(&deg[dst], 1);
}

__global__ __launch_bounds__(256) void scan_part(const int* __restrict__ deg,
                                                 int* __restrict__ part, int n) {
  __shared__ int red[256];
  const int tid = threadIdx.x;
  int s = 0;
  #pragma unroll
  for (int j = 0; j < 8; ++j) {
    const int idx = blockIdx.x * 2048 + j * 256 + tid;
    if (idx < n) s += deg[idx];
  }
  red[tid] = s;
  __syncthreads();
  for (int o = 128; o > 0; o >>= 1) {
    if (tid < o) red[tid] += red[tid + o];
    __syncthreads();
  }
  if (tid == 0) part[blockIdx.x] = red[0];
}

__global__ __launch_bounds__(256) void scan_fin(
    const int* __restrict__ deg, const int* __restrict__ part,
    int* __restrict__ off, int* __restrict__ cursor, int n, int nblk) {
  __shared__ int sd[256];
  __shared__ int s_pref;
  const int tid = threadIdx.x;
  if (tid == 0) {
    int p = 0;
    for (int i = 0; i < blockIdx.x; ++i) p += part[i];
    s_pref = p;
  }
  const int base = blockIdx.x * 2048 + tid * 8;
  int v[8];
  int tsum = 0;
  #pragma unroll
  for (int j = 0; j < 8; ++j) {
    const int idx = base + j;
    v[j] = (idx < n) ? deg[idx] : 0;
    tsum += v[j];
  }
  sd[tid] = tsum;
  __syncthreads();
  for (int o = 1; o < 256; o <<= 1) {
    const int t = (tid >= o) ? sd[tid - o] : 0;
    __syncthreads();
    sd[tid] += t;
    __syncthreads();
  }
  int start = s_pref + sd[tid] - tsum;
  #pragma unroll
  for (int j = 0; j < 8; ++j) {
    const int idx = base + j;
    if (idx < n) { off[idx] = start; cursor[idx] = start; }
    start += v[j];
  }
}

__global__ void scatter_kernel(const int* __restrict__ ei, int* __restrict__ cursor,
                               int* __restrict__ csr_src, int E_, int n) {
  const int i = blockIdx.x * blockDim.x + threadIdx.x;
  const int Et = E_ + n;
  if (i >= Et) return;
  int src, dst;
  if (i < E_) { src = ei[i]; dst = ei[E_ + i]; }
  else        { src = i - E_; dst = i - E_; }
  const int pos = atomicAdd(&cursor[dst], 1);
  csr_src[pos] = src;
}

// ===================== per-destination gather + softmax ====================
// One wave per node, fp16 xh. Lane half (bit5) owns edge j / j+1 of each
// pair; sublane (lane&31) owns 8 channels (16B load).
__device__ __forceinline__ void edge_step(
    const __half* __restrict__ xh, const float* __restrict__ aS,
    const int* __restrict__ csr, int o, int d, int jj, int h, int sub,
    float adst, float& s, float* acc)
{
  const bool valid = jj < d;
  const int src = csr[o + (valid ? jj : 0)];
  float e = aS[src * 8 + h] + adst;
  e = (e > 0.f) ? e : 0.2f * e;
  const float p = valid ? __expf(e) : 0.f;
  const float4 raw = *(const float4*)(xh + (size_t)src * 256 + sub * 8);
  const __half2* hp = (const __half2*)&raw;
  float2 f;
  f = __half22float2(hp[0]); acc[0] += p * f.x; acc[1] += p * f.y;
  f = __half22float2(hp[1]); acc[2] += p * f.x; acc[3] += p * f.y;
  f = __half22float2(hp[2]); acc[4] += p * f.x; acc[5] += p * f.y;
  f = __half22float2(hp[3]); acc[6] += p * f.x; acc[7] += p * f.y;
  s += p;
}

template<bool RELU>
__global__ __launch_bounds__(128) void gat_gather(
    const __half* __restrict__ xh, const float* __restrict__ aS,
    const float* __restrict__ aD, const int* __restrict__ off,
    const int* __restrict__ deg, const int* __restrict__ csr_src,
    const float* __restrict__ bias, float* __restrict__ out, int n)
{
  const int wid  = threadIdx.x >> 6;
  const int lane = threadIdx.x & 63;
  const int node = blockIdx.x * 2 + wid;
  if (node >= n) return;

  const int half = lane >> 5;     // edge slot within pair
  const int sub  = lane & 31;     // channels sub*8 .. sub*8+7
  const int h    = sub >> 2;      // head
  const float adst = aD[(size_t)node * 8 + h];
  const int o = off[node];
  const int d = deg[node];        // >= 1 (self loop)

  float s = 0.f;
  float acc[8] = {0.f, 0.f, 0.f, 0.f, 0.f, 0.f, 0.f, 0.f};

  for (int j = 0; j < d; j += 4) {
    edge_step(xh, aS, csr_src, o, d, j + half,     h, sub, adst, s, acc);
    edge_step(xh, aS, csr_src, o, d, j + 2 + half, h, sub, adst, s, acc);
  }

  // merge the two edge-halves (bit 5)
  s += __shfl_xor(s, 32);
  #pragma unroll
  for (int k = 0; k < 8; ++k) acc[k] += __shfl_xor(acc[k], 32);

  const float inv = 1.f / s;      // per-head normalization
  #pragma unroll
  for (int k = 0; k < 8; ++k) acc[k] *= inv;

  // mean over heads: bits 2..4 of sublane index the head
  #pragma unroll
  for (int msk = 4; msk <= 16; msk <<= 1) {
    #pragma unroll
    for (int k = 0; k < 8; ++k) acc[k] += __shfl_xor(acc[k], msk);
  }

  if (lane < 4) {                 // lane owns out channels lane*8..+7
    const float4* b4 = (const float4*)bias;
    const float4 bb0 = b4[lane * 2], bb1 = b4[lane * 2 + 1];
    float4 o0, o1;
    o0.x = acc[0] * 0.125f + bb0.x; o0.y = acc[1] * 0.125f + bb0.y;
    o0.z = acc[2] * 0.125f + bb0.z; o0.w = acc[3] * 0.125f + bb0.w;
    o1.x = acc[4] * 0.125f + bb1.x; o1.y = acc[5] * 0.125f + bb1.y;
    o1.z = acc[6] * 0.125f + bb1.z; o1.w = acc[7] * 0.125f + bb1.w;
    if (RELU) {
      o0.x = fmaxf(o0.x, 0.f); o0.y = fmaxf(o0.y, 0.f);
      o0.z = fmaxf(o0.z, 0.f); o0.w = fmaxf(o0.w, 0.f);
      o1.x = fmaxf(o1.x, 0.f); o1.y = fmaxf(o1.y, 0.f);
      o1.z = fmaxf(o1.z, 0.f); o1.w = fmaxf(o1.w, 0.f);
    }
    float4* op = (float4*)(out + (size_t)node * 32 + lane * 8);
    op[0] = o0; op[1] = o1;
  }
}

// ================================ decoder ==================================
__global__ __launch_bounds__(256) void decode_kernel(
    const float* __restrict__ z, const int* __restrict__ eli,
    float* __restrict__ out, int el)
{
  const int t = blockIdx.x * blockDim.x + threadIdx.x;
  const int pair = t >> 3;
  const int sub  = t & 7;
  if (pair >= el) return;
  const int a = eli[pair];
  const int b = eli[el + pair];
  const float4* z4 = reinterpret_cast<const float4*>(z);
  const float4 va = z4[(size_t)a * 8 + sub];
  const float4 vb = z4[(size_t)b * 8 + sub];
  float dp = va.x * vb.x + va.y * vb.y + va.z * vb.z + va.w * vb.w;
  dp += __shfl_xor(dp, 1);
  dp += __shfl_xor(dp, 2);
  dp += __shfl_xor(dp, 4);
  if (sub == 0) out[pair] = dp;
}

// ================================ launcher =================================
extern "C" void kernel_launch(void* const* d_in, const int* in_sizes, int n_in,
                              void* d_out, int out_size, void* d_ws, size_t ws_size,
                              hipStream_t stream)
{
  const float* x   = (const float*)d_in[0];
  const int*   ei  = (const int*)  d_in[1];
  const int*   eli = (const int*)  d_in[2];
  const float* W1  = (const float*)d_in[3];
  const float* as1 = (const float*)d_in[4];
  const float* ad1 = (const float*)d_in[5];
  const float* b1  = (const float*)d_in[6];
  const float* W2  = (const float*)d_in[7];
  const float* as2 = (const float*)d_in[8];
  const float* ad2 = (const float*)d_in[9];
  const float* b2  = (const float*)d_in[10];
  float* out = (float*)d_out;

  const int n  = in_sizes[0] / 128;   // 50000
  const int e  = in_sizes[1] / 2;     // 400000
  const int el = in_sizes[2] / 2;     // 100000
  const int et = e + n;

  // workspace carve-up (16B-aligned chunks)
  char* p = (char*)d_ws;
  __half* xh       = (__half*)p;    p += (size_t)n * 256 * 2;  // 25.6 MB fp16
  float* aS        = (float*)p;     p += (size_t)n * 8 * 4;
  float* aD        = (float*)p;     p += (size_t)n * 8 * 4;
  int*   deg       = (int*)  p;     p += (size_t)n * 4;
  int*   off       = (int*)  p;     p += (size_t)n * 4;
  int*   cursor    = (int*)  p;     p += (size_t)n * 4;
  int*   part      = (int*)  p;     p += 128 * 4;
  int*   csr_src   = (int*)  p;     p += (size_t)et * 4;
  float* h1        = (float*)p;     p += (size_t)n * 32 * 4;
  float* z         = (float*)p;     p += (size_t)n * 32 * 4;
  _Float16* W1p    = (_Float16*)p;  p += (size_t)16 * 272 * 8 * 2;
  _Float16* W2p    = (_Float16*)p;  p += (size_t)4 * 272 * 8 * 2;

  const int nblk = (n + 2047) / 2048;
  const int gblk = (n + 63) / 64;     // mfma gemm: 4 waves x 16 rows

  hipMemsetAsync(deg, 0, (size_t)n * 4, stream);

  // CSR build + fused W packs
  count_kernel<<<(et + 255) / 256, 256, 0, stream>>>(ei, deg, e, n);
  scan_part<<<nblk, 256, 0, stream>>>(deg, part, n);
  scan_fin<<<nblk, 256, 0, stream>>>(deg, part, off, cursor, n, nblk);
  scatter_kernel<<<(et + 255) / 256, 256, 0, stream>>>(ei, cursor, csr_src, e, n);
  wtrans_both<<<20, 320, 0, stream>>>(W1, as1, ad1, W1p, W2, as2, ad2, W2p);

  // layer 1
  mfma_gemm_att<128><<<gblk, 256, 0, stream>>>(x, W1p, xh, aS, aD, n);
  gat_gather<true><<<(n + 1) / 2, 128, 0, stream>>>(xh, aS, aD, off, deg, csr_src,
                                                    b1, h1, n);
  // layer 2
  mfma_gemm_att<32><<<gblk, 256, 0, stream>>>(h1, W2p, xh, aS, aD, n);
  gat_gather<false><<<(n + 1) / 2, 128, 0, stream>>>(xh, aS, aD, off, deg, csr_src,
                                                     b2, z, n);
  // decoder
  decode_kernel<<<(el * 8 + 255) / 256, 256, 0, stream>>>(z, eli, out, el);
}

// Round 8
// 190.403 us; speedup vs baseline: 1.6006x; 1.1130x over previous
//
#include <hip/hip_runtime.h>
#include <hip/hip_fp16.h>
#include <math.h>
#include <stdint.h>

// ---------------------------------------------------------------------------
//   N=50000 nodes, E=400000 edges (+N self loops), EL=100000 label pairs
//   H=8 heads, IN=128, HID=32, OUT=32  -> 256 value cols + 16 logit cols = 272
//   xh, h1 stored FP16. CSR rows padded to x4 with sentinel node n
//   (aS[n] = -1e30 -> p = 0; xh[n] zeroed) so the gather loop is mask-free.
// ---------------------------------------------------------------------------

typedef __attribute__((ext_vector_type(8))) _Float16 f16x8;  // 8 f16 = 4 VGPR
typedef __attribute__((ext_vector_type(4))) float f32x4;

// v_fma_mix_f32: acc += p(f32) * f16half(x)   (src1 fp16 lo/hi via op_sel)
__device__ __forceinline__ void fmamix_lo(float& a, float p, uint32_t x) {
  asm("v_fma_mix_f32 %0, %1, %2, %0 op_sel_hi:[0,1,0]"
      : "+v"(a) : "v"(p), "v"(x));
}
__device__ __forceinline__ void fmamix_hi(float& a, float p, uint32_t x) {
  asm("v_fma_mix_f32 %0, %1, %2, %0 op_sel:[0,1,0] op_sel_hi:[0,1,0]"
      : "+v"(a) : "v"(p), "v"(x));
}

// ==== W pack: [K][256] f32 (+att vecs) -> [K/8][272][8] fp16 ===============
__device__ __forceinline__ void wtrans_body(
    const float* __restrict__ W, const float* __restrict__ attS,
    const float* __restrict__ attD, _Float16* __restrict__ Wp, int chunk)
{
  const int col = threadIdx.x;
  if (col >= 272) return;
  float w[8];
  if (col < 256) {
    #pragma unroll
    for (int e = 0; e < 8; ++e)
      w[e] = W[(size_t)(chunk * 8 + e) * 256 + col];
  } else {
    const int h = (col - 256) & 7;
    const float* att = (col < 264) ? attS : attD;
    #pragma unroll
    for (int e = 0; e < 8; ++e) {
      float s = 0.f;
      for (int c = 0; c < 32; ++c)
        s += W[(size_t)(chunk * 8 + e) * 256 + h * 32 + c] * att[h * 32 + c];
      w[e] = s;
    }
  }
  f16x8 v;
  #pragma unroll
  for (int e = 0; e < 8; ++e) v[e] = (_Float16)w[e];
  *(f16x8*)(Wp + ((size_t)chunk * 272 + col) * 8) = v;
}

// fused: blocks 0..15 W1-pack, 16..19 W2-pack, 20.. degree count
__global__ __launch_bounds__(320) void count_wtrans(
    const int* __restrict__ ei, int* __restrict__ deg, int E_, int n,
    const float* __restrict__ W1, const float* __restrict__ as1,
    const float* __restrict__ ad1, _Float16* __restrict__ W1p,
    const float* __restrict__ W2, const float* __restrict__ as2,
    const float* __restrict__ ad2, _Float16* __restrict__ W2p)
{
  const int b = blockIdx.x;
  if (b < 16) { wtrans_body(W1, as1, ad1, W1p, b); return; }
  if (b < 20) { wtrans_body(W2, as2, ad2, W2p, b - 16); return; }
  const int i = (b - 20) * 320 + threadIdx.x;
  const int Et = E_ + n;
  if (i >= Et) return;
  const int dst = (i < E_) ? ei[E_ + i] : (i - E_);
  atomicAdd(&deg[dst], 1);
}

// ================= fp16 MFMA GEMM, swapped operands ========================
// [xh(fp16) | aS | aD] = X @ Wpacked, single-pass 16x16x32 f16 MFMA.
// acc[nt][reg] = C[r0+lr][nt*16 + lg*4 + reg]; LDS-staged coalesced epilogue.
template<int K, bool XHALF>
__global__ __launch_bounds__(256) void mfma_gemm_att(
    const void* __restrict__ Xv, const _Float16* __restrict__ Wp,
    __half* __restrict__ xh, float* __restrict__ aS, float* __restrict__ aD,
    int n)
{
  constexpr int KC = K / 32;
  __shared__ _Float16 tile[4][16][264];
  const int lane = threadIdx.x & 63;
  const int wid  = threadIdx.x >> 6;
  const int lr   = lane & 15;
  const int lg   = lane >> 4;
  const int r0   = (blockIdx.x * 4 + wid) * 16;
  if (r0 >= n) return;

  const int arow = r0 + lr;
  const bool aok = arow < n;

  f16x8 A[KC];
  #pragma unroll
  for (int kc = 0; kc < KC; ++kc) {
    if constexpr (XHALF) {
      const __half* xp = (const __half*)Xv + (size_t)arow * K;
      if (aok) {
        A[kc] = *(const f16x8*)(xp + kc * 32 + lg * 8);
      } else {
        #pragma unroll
        for (int e = 0; e < 8; ++e) A[kc][e] = (_Float16)0.f;
      }
    } else {
      const float* xp = (const float*)Xv + (size_t)arow * K;
      float a[8];
      if (aok) {
        const float4 p0 = *(const float4*)(xp + kc * 32 + lg * 8);
        const float4 p1 = *(const float4*)(xp + kc * 32 + lg * 8 + 4);
        a[0] = p0.x; a[1] = p0.y; a[2] = p0.z; a[3] = p0.w;
        a[4] = p1.x; a[5] = p1.y; a[6] = p1.z; a[7] = p1.w;
      } else {
        #pragma unroll
        for (int e = 0; e < 8; ++e) a[e] = 0.f;
      }
      #pragma unroll
      for (int e = 0; e < 8; ++e) A[kc][e] = (_Float16)a[e];
    }
  }

  f32x4 acc[17];
  #pragma unroll
  for (int i = 0; i < 17; ++i) acc[i] = (f32x4){0.f, 0.f, 0.f, 0.f};

  const f16x8* WH = (const f16x8*)Wp;
  #pragma unroll
  for (int kc = 0; kc < KC; ++kc) {
    const f16x8* wrow = WH + (size_t)(kc * 4 + lg) * 272;
    #pragma unroll
    for (int nt = 0; nt < 17; ++nt) {
      const f16x8 B = wrow[nt * 16 + lr];
      acc[nt] = __builtin_amdgcn_mfma_f32_16x16x32_f16(B, A[kc], acc[nt], 0, 0, 0);
    }
  }

  const int orow = r0 + lr;
  if (orow < n) {
    if (lg == 0) *(f32x4*)(aS + (size_t)orow * 8)     = acc[16];
    if (lg == 1) *(f32x4*)(aS + (size_t)orow * 8 + 4) = acc[16];
    if (lg == 2) *(f32x4*)(aD + (size_t)orow * 8)     = acc[16];
    if (lg == 3) *(f32x4*)(aD + (size_t)orow * 8 + 4) = acc[16];
  }

  #pragma unroll
  for (int nt = 0; nt < 16; ++nt) {
    _Float16 pk[4];
    #pragma unroll
    for (int j = 0; j < 4; ++j) pk[j] = (_Float16)acc[nt][j];
    *(uint2*)&tile[wid][lr][nt * 16 + lg * 4] = *(uint2*)pk;
  }
  __builtin_amdgcn_s_waitcnt(0);  // wave-private tile: drain lgkm then re-read
  const int crow = lane >> 5;
  const int cch  = lane & 31;
  #pragma unroll
  for (int ps = 0; ps < 8; ++ps) {
    const int row = ps * 2 + crow;
    const int grow = r0 + row;
    const uint2* src = (const uint2*)&tile[wid][row][cch * 8];
    if (grow < n) {
      uint2 v0 = src[0], v1 = src[1];
      *(uint4*)(xh + (size_t)grow * 256 + cch * 8) =
          make_uint4(v0.x, v0.y, v1.x, v1.y);
    }
  }
}

// ===================== scan (padded degrees) ===============================
__global__ __launch_bounds__(256) void scan_part(const int* __restrict__ deg,
                                                 int* __restrict__ part, int n) {
  __shared__ int red[256];
  const int tid = threadIdx.x;
  int s = 0;
  #pragma unroll
  for (int j = 0; j < 8; ++j) {
    const int idx = blockIdx.x * 2048 + j * 256 + tid;
    if (idx < n) s += (deg[idx] + 3) & ~3;
  }
  red[tid] = s;
  __syncthreads();
  for (int o = 128; o > 0; o >>= 1) {
    if (tid < o) red[tid] += red[tid + o];
    __syncthreads();
  }
  if (tid == 0) part[blockIdx.x] = red[0];
}

// scan_fin: offsets from padded degrees, sentinel-fill pad slots, and
// (block 0) re-init sentinel row xh[n]=0 / aS[n]=-1e30 every call.
__global__ __launch_bounds__(256) void scan_fin(
    const int* __restrict__ deg, const int* __restrict__ part,
    int* __restrict__ off, int* __restrict__ cursor, int* __restrict__ csr,
    __half* __restrict__ xh, float* __restrict__ aS, int n) {
  __shared__ int sd[256];
  __shared__ int s_pref;
  const int tid = threadIdx.x;
  if (blockIdx.x == 0) {
    if (tid < 32) ((uint4*)((char*)xh + (size_t)n * 512))[tid] = make_uint4(0, 0, 0, 0);
    else if (tid < 40) aS[(size_t)n * 8 + (tid - 32)] = -1e30f;
  }
  if (tid == 0) {
    int p = 0;
    for (int i = 0; i < blockIdx.x; ++i) p += part[i];
    s_pref = p;
  }
  const int base = blockIdx.x * 2048 + tid * 8;
  int dg[8], pv[8];
  int tsum = 0;
  #pragma unroll
  for (int j = 0; j < 8; ++j) {
    const int idx = base + j;
    dg[j] = (idx < n) ? deg[idx] : 0;
    pv[j] = (dg[j] + 3) & ~3;
    tsum += pv[j];
  }
  sd[tid] = tsum;
  __syncthreads();
  for (int o = 1; o < 256; o <<= 1) {
    const int t = (tid >= o) ? sd[tid - o] : 0;
    __syncthreads();
    sd[tid] += t;
    __syncthreads();
  }
  int start = s_pref + sd[tid] - tsum;
  #pragma unroll
  for (int j = 0; j < 8; ++j) {
    const int idx = base + j;
    if (idx < n) {
      off[idx] = start; cursor[idx] = start;
      for (int k = dg[j]; k < pv[j]; ++k) csr[start + k] = n;  // sentinel pad
    }
    start += pv[j];
  }
}

__global__ void scatter_kernel(const int* __restrict__ ei, int* __restrict__ cursor,
                               int* __restrict__ csr_src, int E_, int n) {
  const int i = blockIdx.x * blockDim.x + threadIdx.x;
  const int Et = E_ + n;
  if (i >= Et) return;
  int src, dst;
  if (i < E_) { src = ei[i]; dst = ei[E_ + i]; }
  else        { src = i - E_; dst = i - E_; }
  const int pos = atomicAdd(&cursor[dst], 1);
  csr_src[pos] = src;
}

// ===================== per-destination gather + softmax ====================
// One wave per node; lane half (bit5) owns edge j / j+1; sublane owns 8
// channels (16B fp16 load). Mask-free padded loop; fma_mix accumulation.
__device__ __forceinline__ void edge_step(
    const char* __restrict__ xhb, const float* __restrict__ aSf,
    const int* __restrict__ csr, int o, int jj, int h, int subo,
    float adst, float& s, float* acc)
{
  const uint32_t so = (uint32_t)csr[o + jj];
  const float av = aSf[so * 8u + (uint32_t)h];
  float e = av + adst;
  e = fmaxf(e, 0.2f * e);                 // leaky_relu slope 0.2
  const float p = __expf(e);
  const uint4 raw = *(const uint4*)(xhb + ((so << 9) + (uint32_t)subo));
  fmamix_lo(acc[0], p, raw.x); fmamix_hi(acc[1], p, raw.x);
  fmamix_lo(acc[2], p, raw.y); fmamix_hi(acc[3], p, raw.y);
  fmamix_lo(acc[4], p, raw.z); fmamix_hi(acc[5], p, raw.z);
  fmamix_lo(acc[6], p, raw.w); fmamix_hi(acc[7], p, raw.w);
  s += p;
}

template<bool RELU, typename OUT_T>
__global__ __launch_bounds__(128) void gat_gather(
    const __half* __restrict__ xh, const float* __restrict__ aS,
    const float* __restrict__ aD, const int* __restrict__ off,
    const int* __restrict__ deg, const int* __restrict__ csr_src,
    const float* __restrict__ bias, OUT_T* __restrict__ out, int n)
{
  const int wid  = threadIdx.x >> 6;
  const int lane = threadIdx.x & 63;
  const int node = blockIdx.x * 2 + wid;
  if (node >= n) return;

  const int half = lane >> 5;
  const int sub  = lane & 31;
  const int subo = sub * 16;      // byte offset of this lane's 8 channels
  const int h    = sub >> 2;
  const float adst = aD[(size_t)node * 8 + h];
  const int o  = off[node];
  const int d  = deg[node];       // >= 1 (self loop)
  const int pd = (d + 3) & ~3;    // padded length (sentinels -> p = 0)

  float s = 0.f;
  float acc[8] = {0.f, 0.f, 0.f, 0.f, 0.f, 0.f, 0.f, 0.f};
  const char* xhb = (const char*)xh;

  for (int j = 0; j < pd; j += 4) {
    edge_step(xhb, aS, csr_src, o, j + half,     h, subo, adst, s, acc);
    edge_step(xhb, aS, csr_src, o, j + 2 + half, h, subo, adst, s, acc);
  }

  // merge edge-halves (bit 5)
  s += __shfl_xor(s, 32);
  #pragma unroll
  for (int k = 0; k < 8; ++k) acc[k] += __shfl_xor(acc[k], 32);

  const float inv = 1.f / s;
  #pragma unroll
  for (int k = 0; k < 8; ++k) acc[k] *= inv;

  // mean over heads (bits 2..4 of sublane)
  #pragma unroll
  for (int msk = 4; msk <= 16; msk <<= 1) {
    #pragma unroll
    for (int k = 0; k < 8; ++k) acc[k] += __shfl_xor(acc[k], msk);
  }

  if (lane < 4) {                 // lane owns out channels lane*8..+7
    const float4* b4 = (const float4*)bias;
    const float4 bb0 = b4[lane * 2], bb1 = b4[lane * 2 + 1];
    float o8[8];
    o8[0] = acc[0] * 0.125f + bb0.x; o8[1] = acc[1] * 0.125f + bb0.y;
    o8[2] = acc[2] * 0.125f + bb0.z; o8[3] = acc[3] * 0.125f + bb0.w;
    o8[4] = acc[4] * 0.125f + bb1.x; o8[5] = acc[5] * 0.125f + bb1.y;
    o8[6] = acc[6] * 0.125f + bb1.z; o8[7] = acc[7] * 0.125f + bb1.w;
    if (RELU) {
      #pragma unroll
      for (int k = 0; k < 8; ++k) o8[k] = fmaxf(o8[k], 0.f);
    }
    if constexpr (sizeof(OUT_T) == 2) {   // fp16 output (h1)
      union { __half2 h2[4]; uint4 u; } pk;
      pk.h2[0] = __float22half2_rn(make_float2(o8[0], o8[1]));
      pk.h2[1] = __float22half2_rn(make_float2(o8[2], o8[3]));
      pk.h2[2] = __float22half2_rn(make_float2(o8[4], o8[5]));
      pk.h2[3] = __float22half2_rn(make_float2(o8[6], o8[7]));
      *(uint4*)((__half*)out + (size_t)node * 32 + lane * 8) = pk.u;
    } else {                               // fp32 output (z)
      float4 v0 = make_float4(o8[0], o8[1], o8[2], o8[3]);
      float4 v1 = make_float4(o8[4], o8[5], o8[6], o8[7]);
      float4* op = (float4*)((float*)out + (size_t)node * 32 + lane * 8);
      op[0] = v0; op[1] = v1;
    }
  }
}

// ================================ decoder ==================================
__global__ __launch_bounds__(256) void decode_kernel(
    const float* __restrict__ z, const int* __restrict__ eli,
    float* __restrict__ out, int el)
{
  const int t = blockIdx.x * blockDim.x + threadIdx.x;
  const int pair = t >> 3;
  const int sub  = t & 7;
  if (pair >= el) return;
  const uint32_t a = (uint32_t)eli[pair];
  const uint32_t b = (uint32_t)eli[el + pair];
  const float4* z4 = reinterpret_cast<const float4*>(z);
  const float4 va = z4[a * 8u + sub];
  const float4 vb = z4[b * 8u + sub];
  float dp = va.x * vb.x + va.y * vb.y + va.z * vb.z + va.w * vb.w;
  dp += __shfl_xor(dp, 1);
  dp += __shfl_xor(dp, 2);
  dp += __shfl_xor(dp, 4);
  if (sub == 0) out[pair] = dp;
}

// ================================ launcher =================================
extern "C" void kernel_launch(void* const* d_in, const int* in_sizes, int n_in,
                              void* d_out, int out_size, void* d_ws, size_t ws_size,
                              hipStream_t stream)
{
  const float* x   = (const float*)d_in[0];
  const int*   ei  = (const int*)  d_in[1];
  const int*   eli = (const int*)  d_in[2];
  const float* W1  = (const float*)d_in[3];
  const float* as1 = (const float*)d_in[4];
  const float* ad1 = (const float*)d_in[5];
  const float* b1  = (const float*)d_in[6];
  const float* W2  = (const float*)d_in[7];
  const float* as2 = (const float*)d_in[8];
  const float* ad2 = (const float*)d_in[9];
  const float* b2  = (const float*)d_in[10];
  float* out = (float*)d_out;

  const int n  = in_sizes[0] / 128;   // 50000
  const int e  = in_sizes[1] / 2;     // 400000
  const int el = in_sizes[2] / 2;     // 100000
  const int et = e + n;
  const int slots = et + 3 * n + 64;  // padded CSR capacity

  // workspace carve-up (16B-aligned chunks)
  char* p = (char*)d_ws;
  __half* xh       = (__half*)p;    p += (size_t)(n + 1) * 256 * 2; // +sentinel row
  float* aS        = (float*)p;     p += (size_t)(n + 1) * 8 * 4;   // +sentinel
  float* aD        = (float*)p;     p += (size_t)n * 8 * 4;
  int*   deg       = (int*)  p;     p += (size_t)n * 4;
  int*   off       = (int*)  p;     p += (size_t)n * 4;
  int*   cursor    = (int*)  p;     p += (size_t)n * 4;
  int*   part      = (int*)  p;     p += 128 * 4;
  int*   csr_src   = (int*)  p;     p += (size_t)slots * 4;
  __half* h1       = (__half*)p;    p += (size_t)n * 32 * 2;
  float* z         = (float*)p;     p += (size_t)n * 32 * 4;
  _Float16* W1p    = (_Float16*)p;  p += (size_t)16 * 272 * 8 * 2;
  _Float16* W2p    = (_Float16*)p;  p += (size_t)4 * 272 * 8 * 2;

  const int nblk = (n + 2047) / 2048;
  const int gblk = (n + 63) / 64;

  hipMemsetAsync(deg, 0, (size_t)n * 4, stream);

  // CSR build + W packs (fused into count launch)
  count_wtrans<<<20 + (et + 319) / 320, 320, 0, stream>>>(
      ei, deg, e, n, W1, as1, ad1, W1p, W2, as2, ad2, W2p);
  scan_part<<<nblk, 256, 0, stream>>>(deg, part, n);
  scan_fin<<<nblk, 256, 0, stream>>>(deg, part, off, cursor, csr_src, xh, aS, n);
  scatter_kernel<<<(et + 255) / 256, 256, 0, stream>>>(ei, cursor, csr_src, e, n);

  // layer 1
  mfma_gemm_att<128, false><<<gblk, 256, 0, stream>>>(x, W1p, xh, aS, aD, n);
  gat_gather<true, __half><<<(n + 1) / 2, 128, 0, stream>>>(
      xh, aS, aD, off, deg, csr_src, b1, h1, n);
  // layer 2
  mfma_gemm_att<32, true><<<gblk, 256, 0, stream>>>(h1, W2p, xh, aS, aD, n);
  gat_gather<false, float><<<(n + 1) / 2, 128, 0, stream>>>(
      xh, aS, aD, off, deg, csr_src, b2, z, n);
  // decoder
  decode_kernel<<<(el * 8 + 255) / 256, 256, 0, stream>>>(z, eli, out, el);
}

// Round 9
// 186.705 us; speedup vs baseline: 1.6324x; 1.0198x over previous
//
#include <hip/hip_runtime.h>
#include <hip/hip_fp16.h>
#include <math.h>
#include <stdint.h>

// ---------------------------------------------------------------------------
//   N=50000 nodes, E=400000 edges (+N self loops), EL=100000 label pairs
//   H=8 heads, IN=128, HID=32, OUT=32  -> 256 value cols + 16 logit cols = 272
//   xh, h1 stored FP16. CSR rows padded to x4 with sentinel node n
//   (aS[n] = -1e30 -> p = 0; xh[n] zeroed) so the gather loop is mask-free.
// ---------------------------------------------------------------------------

typedef __attribute__((ext_vector_type(8))) _Float16 f16x8;  // 8 f16 = 4 VGPR
typedef __attribute__((ext_vector_type(4))) float f32x4;

// v_fma_mix_f32: acc += p(f32) * f16half(x)   (src1 fp16 lo/hi via op_sel)
__device__ __forceinline__ void fmamix_lo(float& a, float p, uint32_t x) {
  asm("v_fma_mix_f32 %0, %1, %2, %0 op_sel_hi:[0,1,0]"
      : "+v"(a) : "v"(p), "v"(x));
}
__device__ __forceinline__ void fmamix_hi(float& a, float p, uint32_t x) {
  asm("v_fma_mix_f32 %0, %1, %2, %0 op_sel:[0,1,0] op_sel_hi:[0,1,0]"
      : "+v"(a) : "v"(p), "v"(x));
}

// ======================== deg zeroing (memset repl) ========================
__global__ __launch_bounds__(256) void zero_deg(uint4* __restrict__ p, int n4) {
  const int i = blockIdx.x * 256 + threadIdx.x;
  if (i < n4) p[i] = make_uint4(0, 0, 0, 0);
}

// ==== W pack: [K][256] f32 (+att vecs) -> [K/8][272][8] fp16 ===============
__device__ __forceinline__ void wtrans_body(
    const float* __restrict__ W, const float* __restrict__ attS,
    const float* __restrict__ attD, _Float16* __restrict__ Wp, int chunk)
{
  const int col = threadIdx.x;
  if (col >= 272) return;
  float w[8];
  if (col < 256) {
    #pragma unroll
    for (int e = 0; e < 8; ++e)
      w[e] = W[(size_t)(chunk * 8 + e) * 256 + col];
  } else {
    const int h = (col - 256) & 7;
    const float* att = (col < 264) ? attS : attD;
    #pragma unroll
    for (int e = 0; e < 8; ++e) {
      float s = 0.f;
      for (int c = 0; c < 32; ++c)
        s += W[(size_t)(chunk * 8 + e) * 256 + h * 32 + c] * att[h * 32 + c];
      w[e] = s;
    }
  }
  f16x8 v;
  #pragma unroll
  for (int e = 0; e < 8; ++e) v[e] = (_Float16)w[e];
  *(f16x8*)(Wp + ((size_t)chunk * 272 + col) * 8) = v;
}

// fused: blocks 0..15 W1-pack, 16..19 W2-pack, 20.. degree count
__global__ __launch_bounds__(320) void count_wtrans(
    const int* __restrict__ ei, int* __restrict__ deg, int E_, int n,
    const float* __restrict__ W1, const float* __restrict__ as1,
    const float* __restrict__ ad1, _Float16* __restrict__ W1p,
    const float* __restrict__ W2, const float* __restrict__ as2,
    const float* __restrict__ ad2, _Float16* __restrict__ W2p)
{
  const int b = blockIdx.x;
  if (b < 16) { wtrans_body(W1, as1, ad1, W1p, b); return; }
  if (b < 20) { wtrans_body(W2, as2, ad2, W2p, b - 16); return; }
  const int i = (b - 20) * 320 + threadIdx.x;
  const int Et = E_ + n;
  if (i >= Et) return;
  const int dst = (i < E_) ? ei[E_ + i] : (i - E_);
  atomicAdd(&deg[dst], 1);
}

// ================= fp16 MFMA GEMM, swapped operands ========================
template<int K, bool XHALF>
__global__ __launch_bounds__(256) void mfma_gemm_att(
    const void* __restrict__ Xv, const _Float16* __restrict__ Wp,
    __half* __restrict__ xh, float* __restrict__ aS, float* __restrict__ aD,
    int n)
{
  constexpr int KC = K / 32;
  __shared__ _Float16 tile[4][16][264];
  const int lane = threadIdx.x & 63;
  const int wid  = threadIdx.x >> 6;
  const int lr   = lane & 15;
  const int lg   = lane >> 4;
  const int r0   = (blockIdx.x * 4 + wid) * 16;
  if (r0 >= n) return;

  const int arow = r0 + lr;
  const bool aok = arow < n;

  f16x8 A[KC];
  #pragma unroll
  for (int kc = 0; kc < KC; ++kc) {
    if constexpr (XHALF) {
      const __half* xp = (const __half*)Xv + (size_t)arow * K;
      if (aok) {
        A[kc] = *(const f16x8*)(xp + kc * 32 + lg * 8);
      } else {
        #pragma unroll
        for (int e = 0; e < 8; ++e) A[kc][e] = (_Float16)0.f;
      }
    } else {
      const float* xp = (const float*)Xv + (size_t)arow * K;
      float a[8];
      if (aok) {
        const float4 p0 = *(const float4*)(xp + kc * 32 + lg * 8);
        const float4 p1 = *(const float4*)(xp + kc * 32 + lg * 8 + 4);
        a[0] = p0.x; a[1] = p0.y; a[2] = p0.z; a[3] = p0.w;
        a[4] = p1.x; a[5] = p1.y; a[6] = p1.z; a[7] = p1.w;
      } else {
        #pragma unroll
        for (int e = 0; e < 8; ++e) a[e] = 0.f;
      }
      #pragma unroll
      for (int e = 0; e < 8; ++e) A[kc][e] = (_Float16)a[e];
    }
  }

  f32x4 acc[17];
  #pragma unroll
  for (int i = 0; i < 17; ++i) acc[i] = (f32x4){0.f, 0.f, 0.f, 0.f};

  const f16x8* WH = (const f16x8*)Wp;
  #pragma unroll
  for (int kc = 0; kc < KC; ++kc) {
    const f16x8* wrow = WH + (size_t)(kc * 4 + lg) * 272;
    #pragma unroll
    for (int nt = 0; nt < 17; ++nt) {
      const f16x8 B = wrow[nt * 16 + lr];
      acc[nt] = __builtin_amdgcn_mfma_f32_16x16x32_f16(B, A[kc], acc[nt], 0, 0, 0);
    }
  }

  const int orow = r0 + lr;
  if (orow < n) {
    if (lg == 0) *(f32x4*)(aS + (size_t)orow * 8)     = acc[16];
    if (lg == 1) *(f32x4*)(aS + (size_t)orow * 8 + 4) = acc[16];
    if (lg == 2) *(f32x4*)(aD + (size_t)orow * 8)     = acc[16];
    if (lg == 3) *(f32x4*)(aD + (size_t)orow * 8 + 4) = acc[16];
  }

  #pragma unroll
  for (int nt = 0; nt < 16; ++nt) {
    _Float16 pk[4];
    #pragma unroll
    for (int j = 0; j < 4; ++j) pk[j] = (_Float16)acc[nt][j];
    *(uint2*)&tile[wid][lr][nt * 16 + lg * 4] = *(uint2*)pk;
  }
  __builtin_amdgcn_s_waitcnt(0);  // wave-private tile: drain lgkm then re-read
  const int crow = lane >> 5;
  const int cch  = lane & 31;
  #pragma unroll
  for (int ps = 0; ps < 8; ++ps) {
    const int row = ps * 2 + crow;
    const int grow = r0 + row;
    const uint2* src = (const uint2*)&tile[wid][row][cch * 8];
    if (grow < n) {
      uint2 v0 = src[0], v1 = src[1];
      *(uint4*)(xh + (size_t)grow * 256 + cch * 8) =
          make_uint4(v0.x, v0.y, v1.x, v1.y);
    }
  }
}

// ===================== scan (padded degrees) ===============================
__global__ __launch_bounds__(256) void scan_part(const int* __restrict__ deg,
                                                 int* __restrict__ part, int n) {
  __shared__ int red[256];
  const int tid = threadIdx.x;
  int s = 0;
  #pragma unroll
  for (int j = 0; j < 8; ++j) {
    const int idx = blockIdx.x * 2048 + j * 256 + tid;
    if (idx < n) s += (deg[idx] + 3) & ~3;
  }
  red[tid] = s;
  __syncthreads();
  for (int o = 128; o > 0; o >>= 1) {
    if (tid < o) red[tid] += red[tid + o];
    __syncthreads();
  }
  if (tid == 0) part[blockIdx.x] = red[0];
}

// scan_fin: padded offsets (incl. off[n]), sentinel-fill pad slots, and
// (block 0) re-init sentinel row xh[n]=0 / aS[n]=-1e30 every call.
__global__ __launch_bounds__(256) void scan_fin(
    const int* __restrict__ deg, const int* __restrict__ part,
    int* __restrict__ off, int* __restrict__ cursor, int* __restrict__ csr,
    __half* __restrict__ xh, float* __restrict__ aS, int n) {
  __shared__ int sd[256];
  __shared__ int s_pref;
  const int tid = threadIdx.x;
  if (blockIdx.x == 0) {
    if (tid < 32) ((uint4*)((char*)xh + (size_t)n * 512))[tid] = make_uint4(0, 0, 0, 0);
    else if (tid < 40) aS[(size_t)n * 8 + (tid - 32)] = -1e30f;
  }
  if (tid == 0) {
    int p = 0;
    for (int i = 0; i < blockIdx.x; ++i) p += part[i];
    s_pref = p;
  }
  const int base = blockIdx.x * 2048 + tid * 8;
  int dg[8], pv[8];
  int tsum = 0;
  #pragma unroll
  for (int j = 0; j < 8; ++j) {
    const int idx = base + j;
    dg[j] = (idx < n) ? deg[idx] : 0;
    pv[j] = (dg[j] + 3) & ~3;
    tsum += pv[j];
  }
  sd[tid] = tsum;
  __syncthreads();
  for (int o = 1; o < 256; o <<= 1) {
    const int t = (tid >= o) ? sd[tid - o] : 0;
    __syncthreads();
    sd[tid] += t;
    __syncthreads();
  }
  int start = s_pref + sd[tid] - tsum;
  #pragma unroll
  for (int j = 0; j < 8; ++j) {
    const int idx = base + j;
    if (idx < n) {
      off[idx] = start; cursor[idx] = start;
      for (int k = dg[j]; k < pv[j]; ++k) csr[start + k] = n;  // sentinel pad
    }
    start += pv[j];
    if (idx == n - 1) off[n] = start;
  }
}

__global__ void scatter_kernel(const int* __restrict__ ei, int* __restrict__ cursor,
                               int* __restrict__ csr_src, int E_, int n) {
  const int i = blockIdx.x * blockDim.x + threadIdx.x;
  const int Et = E_ + n;
  if (i >= Et) return;
  int src, dst;
  if (i < E_) { src = ei[i]; dst = ei[E_ + i]; }
  else        { src = i - E_; dst = i - E_; }
  const int pos = atomicAdd(&cursor[dst], 1);
  csr_src[pos] = src;
}

// ===================== per-destination gather + softmax ====================
// One wave per node. Wave cooperatively loads up to 64 CSR indices at once
// (one coalesced load), then __shfl broadcasts each index -> all aS/xh loads
// in a chunk are independent (deep MLP, no serial csr->load chain).
// Lane half (bit5) owns edge j / j+1; sublane owns 8 channels (16B load).
__device__ __forceinline__ void edge_step(
    const char* __restrict__ xhb, const float* __restrict__ aSf,
    uint32_t so, int h, int subo, float adst, float& s, float* acc)
{
  const float av = aSf[so * 8u + (uint32_t)h];
  float e = av + adst;
  e = fmaxf(e, 0.2f * e);                 // leaky_relu slope 0.2
  const float p = __expf(e);
  const uint4 raw = *(const uint4*)(xhb + ((so << 9) + (uint32_t)subo));
  fmamix_lo(acc[0], p, raw.x); fmamix_hi(acc[1], p, raw.x);
  fmamix_lo(acc[2], p, raw.y); fmamix_hi(acc[3], p, raw.y);
  fmamix_lo(acc[4], p, raw.z); fmamix_hi(acc[5], p, raw.z);
  fmamix_lo(acc[6], p, raw.w); fmamix_hi(acc[7], p, raw.w);
  s += p;
}

template<bool RELU, typename OUT_T>
__global__ __launch_bounds__(128) void gat_gather(
    const __half* __restrict__ xh, const float* __restrict__ aS,
    const float* __restrict__ aD, const int* __restrict__ off,
    const int* __restrict__ csr_src, const float* __restrict__ bias,
    OUT_T* __restrict__ out, int n)
{
  const int wid  = threadIdx.x >> 6;
  const int lane = threadIdx.x & 63;
  const int node = blockIdx.x * 2 + wid;
  if (node >= n) return;

  const int half = lane >> 5;
  const int sub  = lane & 31;
  const int subo = sub * 16;      // byte offset of this lane's 8 channels
  const int h    = sub >> 2;
  const float adst = aD[(size_t)node * 8 + h];
  const int o  = off[node];
  const int pd = off[node + 1] - o;   // padded degree (multiple of 4, >= 4)

  float s = 0.f;
  float acc[8] = {0.f, 0.f, 0.f, 0.f, 0.f, 0.f, 0.f, 0.f};
  const char* xhb = (const char*)xh;

  for (int base = 0; base < pd; base += 64) {
    const int chunk = min(64, pd - base);            // multiple of 4
    const int myidx = (lane < chunk) ? csr_src[o + base + lane] : n;
    for (int j = 0; j < chunk; j += 4) {
      const uint32_t s0 = (uint32_t)__shfl(myidx, j + half);
      const uint32_t s1 = (uint32_t)__shfl(myidx, j + 2 + half);
      edge_step(xhb, aS, s0, h, subo, adst, s, acc);
      edge_step(xhb, aS, s1, h, subo, adst, s, acc);
    }
  }

  // merge edge-halves (bit 5)
  s += __shfl_xor(s, 32);
  #pragma unroll
  for (int k = 0; k < 8; ++k) acc[k] += __shfl_xor(acc[k], 32);

  const float inv = 1.f / s;
  #pragma unroll
  for (int k = 0; k < 8; ++k) acc[k] *= inv;

  // mean over heads (bits 2..4 of sublane)
  #pragma unroll
  for (int msk = 4; msk <= 16; msk <<= 1) {
    #pragma unroll
    for (int k = 0; k < 8; ++k) acc[k] += __shfl_xor(acc[k], msk);
  }

  if (lane < 4) {                 // lane owns out channels lane*8..+7
    const float4* b4 = (const float4*)bias;
    const float4 bb0 = b4[lane * 2], bb1 = b4[lane * 2 + 1];
    float o8[8];
    o8[0] = acc[0] * 0.125f + bb0.x; o8[1] = acc[1] * 0.125f + bb0.y;
    o8[2] = acc[2] * 0.125f + bb0.z; o8[3] = acc[3] * 0.125f + bb0.w;
    o8[4] = acc[4] * 0.125f + bb1.x; o8[5] = acc[5] * 0.125f + bb1.y;
    o8[6] = acc[6] * 0.125f + bb1.z; o8[7] = acc[7] * 0.125f + bb1.w;
    if (RELU) {
      #pragma unroll
      for (int k = 0; k < 8; ++k) o8[k] = fmaxf(o8[k], 0.f);
    }
    if constexpr (sizeof(OUT_T) == 2) {   // fp16 output (h1)
      union { __half2 h2[4]; uint4 u; } pk;
      pk.h2[0] = __float22half2_rn(make_float2(o8[0], o8[1]));
      pk.h2[1] = __float22half2_rn(make_float2(o8[2], o8[3]));
      pk.h2[2] = __float22half2_rn(make_float2(o8[4], o8[5]));
      pk.h2[3] = __float22half2_rn(make_float2(o8[6], o8[7]));
      *(uint4*)((__half*)out + (size_t)node * 32 + lane * 8) = pk.u;
    } else {                               // fp32 output (z)
      float4 v0 = make_float4(o8[0], o8[1], o8[2], o8[3]);
      float4 v1 = make_float4(o8[4], o8[5], o8[6], o8[7]);
      float4* op = (float4*)((float*)out + (size_t)node * 32 + lane * 8);
      op[0] = v0; op[1] = v1;
    }
  }
}

// ================================ decoder ==================================
__global__ __launch_bounds__(256) void decode_kernel(
    const float* __restrict__ z, const int* __restrict__ eli,
    float* __restrict__ out, int el)
{
  const int t = blockIdx.x * blockDim.x + threadIdx.x;
  const int pair = t >> 3;
  const int sub  = t & 7;
  if (pair >= el) return;
  const uint32_t a = (uint32_t)eli[pair];
  const uint32_t b = (uint32_t)eli[el + pair];
  const float4* z4 = reinterpret_cast<const float4*>(z);
  const float4 va = z4[a * 8u + sub];
  const float4 vb = z4[b * 8u + sub];
  float dp = va.x * vb.x + va.y * vb.y + va.z * vb.z + va.w * vb.w;
  dp += __shfl_xor(dp, 1);
  dp += __shfl_xor(dp, 2);
  dp += __shfl_xor(dp, 4);
  if (sub == 0) out[pair] = dp;
}

// ================================ launcher =================================
extern "C" void kernel_launch(void* const* d_in, const int* in_sizes, int n_in,
                              void* d_out, int out_size, void* d_ws, size_t ws_size,
                              hipStream_t stream)
{
  const float* x   = (const float*)d_in[0];
  const int*   ei  = (const int*)  d_in[1];
  const int*   eli = (const int*)  d_in[2];
  const float* W1  = (const float*)d_in[3];
  const float* as1 = (const float*)d_in[4];
  const float* ad1 = (const float*)d_in[5];
  const float* b1  = (const float*)d_in[6];
  const float* W2  = (const float*)d_in[7];
  const float* as2 = (const float*)d_in[8];
  const float* ad2 = (const float*)d_in[9];
  const float* b2  = (const float*)d_in[10];
  float* out = (float*)d_out;

  const int n  = in_sizes[0] / 128;   // 50000
  const int e  = in_sizes[1] / 2;     // 400000
  const int el = in_sizes[2] / 2;     // 100000
  const int et = e + n;
  const int slots = et + 3 * n + 64;  // padded CSR capacity

  // workspace carve-up (16B-aligned chunks)
  char* p = (char*)d_ws;
  __half* xh       = (__half*)p;    p += (size_t)(n + 1) * 256 * 2; // +sentinel row
  float* aS        = (float*)p;     p += (size_t)(n + 1) * 8 * 4;   // +sentinel
  float* aD        = (float*)p;     p += (size_t)n * 8 * 4;
  int*   deg       = (int*)  p;     p += (size_t)((n + 3) & ~3) * 4;
  int*   off       = (int*)  p;     p += (size_t)(n + 4) * 4;       // off[n] used
  int*   cursor    = (int*)  p;     p += (size_t)n * 4;
  int*   part      = (int*)  p;     p += 128 * 4;
  int*   csr_src   = (int*)  p;     p += (size_t)slots * 4;
  __half* h1       = (__half*)p;    p += (size_t)n * 32 * 2;
  float* z         = (float*)p;     p += (size_t)n * 32 * 4;
  _Float16* W1p    = (_Float16*)p;  p += (size_t)16 * 272 * 8 * 2;
  _Float16* W2p    = (_Float16*)p;  p += (size_t)4 * 272 * 8 * 2;

  const int nblk = (n + 2047) / 2048;
  const int gblk = (n + 63) / 64;
  const int n4   = (n + 3) / 4;

  // CSR build + W packs
  zero_deg<<<(n4 + 255) / 256, 256, 0, stream>>>((uint4*)deg, n4);
  count_wtrans<<<20 + (et + 319) / 320, 320, 0, stream>>>(
      ei, deg, e, n, W1, as1, ad1, W1p, W2, as2, ad2, W2p);
  scan_part<<<nblk, 256, 0, stream>>>(deg, part, n);
  scan_fin<<<nblk, 256, 0, stream>>>(deg, part, off, cursor, csr_src, xh, aS, n);
  scatter_kernel<<<(et + 255) / 256, 256, 0, stream>>>(ei, cursor, csr_src, e, n);

  // layer 1
  mfma_gemm_att<128, false><<<gblk, 256, 0, stream>>>(x, W1p, xh, aS, aD, n);
  gat_gather<true, __half><<<(n + 1) / 2, 128, 0, stream>>>(
      xh, aS, aD, off, csr_src, b1, h1, n);
  // layer 2
  mfma_gemm_att<32, true><<<gblk, 256, 0, stream>>>(h1, W2p, xh, aS, aD, n);
  gat_gather<false, float><<<(n + 1) / 2, 128, 0, stream>>>(
      xh, aS, aD, off, csr_src, b2, z, n);
  // decoder
  decode_kernel<<<(el * 8 + 255) / 256, 256, 0, stream>>>(z, eli, out, el);
}

// Round 10
// 184.690 us; speedup vs baseline: 1.6502x; 1.0109x over previous
//
#include <hip/hip_runtime.h>
#include <hip/hip_fp16.h>
#include <math.h>
#include <stdint.h>

// ---------------------------------------------------------------------------
//   N=50000 nodes, E=400000 edges (+N self loops), EL=100000 label pairs
//   H=8 heads, IN=128, HID=32, OUT=32  -> 256 value cols + 16 logit cols = 272
//   xh, h1 stored FP16. CSR rows padded to x4 with sentinel node n
//   (aS[n] = -1e30 -> p = 0; xh[n] zeroed) so the gather loop is mask-free.
//   Gather: one node per 32-lane half-wave (2 independent chains per wave).
// ---------------------------------------------------------------------------

typedef __attribute__((ext_vector_type(8))) _Float16 f16x8;  // 8 f16 = 4 VGPR
typedef __attribute__((ext_vector_type(4))) float f32x4;

// v_fma_mix_f32: acc += p(f32) * f16half(x)   (src1 fp16 lo/hi via op_sel)
__device__ __forceinline__ void fmamix_lo(float& a, float p, uint32_t x) {
  asm("v_fma_mix_f32 %0, %1, %2, %0 op_sel_hi:[0,1,0]"
      : "+v"(a) : "v"(p), "v"(x));
}
__device__ __forceinline__ void fmamix_hi(float& a, float p, uint32_t x) {
  asm("v_fma_mix_f32 %0, %1, %2, %0 op_sel:[0,1,0] op_sel_hi:[0,1,0]"
      : "+v"(a) : "v"(p), "v"(x));
}

// ======================== deg zeroing (memset repl) ========================
__global__ __launch_bounds__(256) void zero_deg(uint4* __restrict__ p, int n4) {
  const int i = blockIdx.x * 256 + threadIdx.x;
  if (i < n4) p[i] = make_uint4(0, 0, 0, 0);
}

// ==== W pack: [K][256] f32 (+att vecs) -> [K/8][272][8] fp16 ===============
__device__ __forceinline__ void wtrans_body(
    const float* __restrict__ W, const float* __restrict__ attS,
    const float* __restrict__ attD, _Float16* __restrict__ Wp, int chunk)
{
  const int col = threadIdx.x;
  if (col >= 272) return;
  float w[8];
  if (col < 256) {
    #pragma unroll
    for (int e = 0; e < 8; ++e)
      w[e] = W[(size_t)(chunk * 8 + e) * 256 + col];
  } else {
    const int h = (col - 256) & 7;
    const float* att = (col < 264) ? attS : attD;
    #pragma unroll
    for (int e = 0; e < 8; ++e) {
      float s = 0.f;
      for (int c = 0; c < 32; ++c)
        s += W[(size_t)(chunk * 8 + e) * 256 + h * 32 + c] * att[h * 32 + c];
      w[e] = s;
    }
  }
  f16x8 v;
  #pragma unroll
  for (int e = 0; e < 8; ++e) v[e] = (_Float16)w[e];
  *(f16x8*)(Wp + ((size_t)chunk * 272 + col) * 8) = v;
}

// fused: blocks 0..15 W1-pack, 16..19 W2-pack, 20.. degree count
__global__ __launch_bounds__(320) void count_wtrans(
    const int* __restrict__ ei, int* __restrict__ deg, int E_, int n,
    const float* __restrict__ W1, const float* __restrict__ as1,
    const float* __restrict__ ad1, _Float16* __restrict__ W1p,
    const float* __restrict__ W2, const float* __restrict__ as2,
    const float* __restrict__ ad2, _Float16* __restrict__ W2p)
{
  const int b = blockIdx.x;
  if (b < 16) { wtrans_body(W1, as1, ad1, W1p, b); return; }
  if (b < 20) { wtrans_body(W2, as2, ad2, W2p, b - 16); return; }
  const int i = (b - 20) * 320 + threadIdx.x;
  const int Et = E_ + n;
  if (i >= Et) return;
  const int dst = (i < E_) ? ei[E_ + i] : (i - E_);
  atomicAdd(&deg[dst], 1);
}

// ================= fp16 MFMA GEMM, swapped operands ========================
template<int K, bool XHALF>
__global__ __launch_bounds__(256) void mfma_gemm_att(
    const void* __restrict__ Xv, const _Float16* __restrict__ Wp,
    __half* __restrict__ xh, float* __restrict__ aS, float* __restrict__ aD,
    int n)
{
  constexpr int KC = K / 32;
  __shared__ _Float16 tile[4][16][264];
  const int lane = threadIdx.x & 63;
  const int wid  = threadIdx.x >> 6;
  const int lr   = lane & 15;
  const int lg   = lane >> 4;
  const int r0   = (blockIdx.x * 4 + wid) * 16;
  if (r0 >= n) return;

  const int arow = r0 + lr;
  const bool aok = arow < n;

  f16x8 A[KC];
  #pragma unroll
  for (int kc = 0; kc < KC; ++kc) {
    if constexpr (XHALF) {
      const __half* xp = (const __half*)Xv + (size_t)arow * K;
      if (aok) {
        A[kc] = *(const f16x8*)(xp + kc * 32 + lg * 8);
      } else {
        #pragma unroll
        for (int e = 0; e < 8; ++e) A[kc][e] = (_Float16)0.f;
      }
    } else {
      const float* xp = (const float*)Xv + (size_t)arow * K;
      float a[8];
      if (aok) {
        const float4 p0 = *(const float4*)(xp + kc * 32 + lg * 8);
        const float4 p1 = *(const float4*)(xp + kc * 32 + lg * 8 + 4);
        a[0] = p0.x; a[1] = p0.y; a[2] = p0.z; a[3] = p0.w;
        a[4] = p1.x; a[5] = p1.y; a[6] = p1.z; a[7] = p1.w;
      } else {
        #pragma unroll
        for (int e = 0; e < 8; ++e) a[e] = 0.f;
      }
      #pragma unroll
      for (int e = 0; e < 8; ++e) A[kc][e] = (_Float16)a[e];
    }
  }

  f32x4 acc[17];
  #pragma unroll
  for (int i = 0; i < 17; ++i) acc[i] = (f32x4){0.f, 0.f, 0.f, 0.f};

  const f16x8* WH = (const f16x8*)Wp;
  #pragma unroll
  for (int kc = 0; kc < KC; ++kc) {
    const f16x8* wrow = WH + (size_t)(kc * 4 + lg) * 272;
    #pragma unroll
    for (int nt = 0; nt < 17; ++nt) {
      const f16x8 B = wrow[nt * 16 + lr];
      acc[nt] = __builtin_amdgcn_mfma_f32_16x16x32_f16(B, A[kc], acc[nt], 0, 0, 0);
    }
  }

  const int orow = r0 + lr;
  if (orow < n) {
    if (lg == 0) *(f32x4*)(aS + (size_t)orow * 8)     = acc[16];
    if (lg == 1) *(f32x4*)(aS + (size_t)orow * 8 + 4) = acc[16];
    if (lg == 2) *(f32x4*)(aD + (size_t)orow * 8)     = acc[16];
    if (lg == 3) *(f32x4*)(aD + (size_t)orow * 8 + 4) = acc[16];
  }

  #pragma unroll
  for (int nt = 0; nt < 16; ++nt) {
    _Float16 pk[4];
    #pragma unroll
    for (int j = 0; j < 4; ++j) pk[j] = (_Float16)acc[nt][j];
    *(uint2*)&tile[wid][lr][nt * 16 + lg * 4] = *(uint2*)pk;
  }
  __builtin_amdgcn_s_waitcnt(0);  // wave-private tile: drain lgkm then re-read
  const int crow = lane >> 5;
  const int cch  = lane & 31;
  #pragma unroll
  for (int ps = 0; ps < 8; ++ps) {
    const int row = ps * 2 + crow;
    const int grow = r0 + row;
    const uint2* src = (const uint2*)&tile[wid][row][cch * 8];
    if (grow < n) {
      uint2 v0 = src[0], v1 = src[1];
      *(uint4*)(xh + (size_t)grow * 256 + cch * 8) =
          make_uint4(v0.x, v0.y, v1.x, v1.y);
    }
  }
}

// ===================== scan (padded degrees) ===============================
__global__ __launch_bounds__(256) void scan_part(const int* __restrict__ deg,
                                                 int* __restrict__ part, int n) {
  __shared__ int red[256];
  const int tid = threadIdx.x;
  int s = 0;
  #pragma unroll
  for (int j = 0; j < 8; ++j) {
    const int idx = blockIdx.x * 2048 + j * 256 + tid;
    if (idx < n) s += (deg[idx] + 3) & ~3;
  }
  red[tid] = s;
  __syncthreads();
  for (int o = 128; o > 0; o >>= 1) {
    if (tid < o) red[tid] += red[tid + o];
    __syncthreads();
  }
  if (tid == 0) part[blockIdx.x] = red[0];
}

// scan_fin: padded offsets (incl. off[n]), sentinel-fill pad slots, and
// (block 0) re-init sentinel row xh[n]=0 / aS[n]=-1e30 every call.
__global__ __launch_bounds__(256) void scan_fin(
    const int* __restrict__ deg, const int* __restrict__ part,
    int* __restrict__ off, int* __restrict__ cursor, int* __restrict__ csr,
    __half* __restrict__ xh, float* __restrict__ aS, int n) {
  __shared__ int sd[256];
  __shared__ int s_pref;
  const int tid = threadIdx.x;
  if (blockIdx.x == 0) {
    if (tid < 32) ((uint4*)((char*)xh + (size_t)n * 512))[tid] = make_uint4(0, 0, 0, 0);
    else if (tid < 40) aS[(size_t)n * 8 + (tid - 32)] = -1e30f;
  }
  if (tid == 0) {
    int p = 0;
    for (int i = 0; i < blockIdx.x; ++i) p += part[i];
    s_pref = p;
  }
  const int base = blockIdx.x * 2048 + tid * 8;
  int dg[8], pv[8];
  int tsum = 0;
  #pragma unroll
  for (int j = 0; j < 8; ++j) {
    const int idx = base + j;
    dg[j] = (idx < n) ? deg[idx] : 0;
    pv[j] = (dg[j] + 3) & ~3;
    tsum += pv[j];
  }
  sd[tid] = tsum;
  __syncthreads();
  for (int o = 1; o < 256; o <<= 1) {
    const int t = (tid >= o) ? sd[tid - o] : 0;
    __syncthreads();
    sd[tid] += t;
    __syncthreads();
  }
  int start = s_pref + sd[tid] - tsum;
  #pragma unroll
  for (int j = 0; j < 8; ++j) {
    const int idx = base + j;
    if (idx < n) {
      off[idx] = start; cursor[idx] = start;
      for (int k = dg[j]; k < pv[j]; ++k) csr[start + k] = n;  // sentinel pad
    }
    start += pv[j];
    if (idx == n - 1) off[n] = start;
  }
}

__global__ void scatter_kernel(const int* __restrict__ ei, int* __restrict__ cursor,
                               int* __restrict__ csr_src, int E_, int n) {
  const int i = blockIdx.x * blockDim.x + threadIdx.x;
  const int Et = E_ + n;
  if (i >= Et) return;
  int src, dst;
  if (i < E_) { src = ei[i]; dst = ei[E_ + i]; }
  else        { src = i - E_; dst = i - E_; }
  const int pos = atomicAdd(&cursor[dst], 1);
  csr_src[pos] = src;
}

// ===================== per-destination gather + softmax ====================
// One node per 32-lane HALF-wave: lanes 0-31 -> node A, 32-63 -> node B.
// Two independent dependency chains per wave + 4-deep inner unroll -> ~4x
// outstanding loads. Sublane owns 8 channels (16B fp16 load). Each half
// cooperatively loads 32 CSR indices; bpermute-broadcast per slot.
__device__ __forceinline__ void edge_step(
    const char* __restrict__ xhb, const float* __restrict__ aSf,
    uint32_t so, int h, int subo, float adst, float& s, float* acc)
{
  const float av = aSf[so * 8u + (uint32_t)h];
  float e = av + adst;
  e = fmaxf(e, 0.2f * e);                 // leaky_relu slope 0.2
  const float p = __expf(e);
  const uint4 raw = *(const uint4*)(xhb + ((so << 9) + (uint32_t)subo));
  fmamix_lo(acc[0], p, raw.x); fmamix_hi(acc[1], p, raw.x);
  fmamix_lo(acc[2], p, raw.y); fmamix_hi(acc[3], p, raw.y);
  fmamix_lo(acc[4], p, raw.z); fmamix_hi(acc[5], p, raw.z);
  fmamix_lo(acc[6], p, raw.w); fmamix_hi(acc[7], p, raw.w);
  s += p;
}

template<bool RELU, typename OUT_T>
__global__ __launch_bounds__(128) void gat_gather(
    const __half* __restrict__ xh, const float* __restrict__ aS,
    const float* __restrict__ aD, const int* __restrict__ off,
    const int* __restrict__ csr_src, const float* __restrict__ bias,
    OUT_T* __restrict__ out, int n)
{
  const int wid  = threadIdx.x >> 6;
  const int lane = threadIdx.x & 63;
  const int hb   = lane & 32;          // half base (0 or 32)
  const int sub  = lane & 31;
  const int node = blockIdx.x * 4 + wid * 2 + (hb >> 5);
  const bool valid = node < n;

  const int subo = sub * 16;           // byte offset of this lane's 8 channels
  const int h    = sub >> 2;           // head
  const float adst = valid ? aD[(size_t)node * 8 + h] : 0.f;
  const int o  = valid ? off[node] : 0;
  const int pd = valid ? (off[node + 1] - o) : 0;  // multiple of 4

  // both halves iterate together to the larger padded degree
  const int pdo   = __shfl_xor(pd, 32);
  const int pdMax = max(pd, pdo);

  float s = 0.f;
  float acc[8] = {0.f, 0.f, 0.f, 0.f, 0.f, 0.f, 0.f, 0.f};
  const char* xhb = (const char*)xh;

  for (int base = 0; base < pdMax; base += 32) {
    // this half's next 32 indices (sentinel beyond own pd)
    const int myidx = (base + sub < pd) ? csr_src[o + base + sub] : n;
    const int cm  = min(32, pdMax - base);
    const int cm4 = (cm + 3) & ~3;     // sentinel-safe round-up
    for (int j = 0; j < cm4; j += 4) {
      const uint32_t i0 = (uint32_t)__shfl(myidx, hb + j);
      const uint32_t i1 = (uint32_t)__shfl(myidx, hb + j + 1);
      const uint32_t i2 = (uint32_t)__shfl(myidx, hb + j + 2);
      const uint32_t i3 = (uint32_t)__shfl(myidx, hb + j + 3);
      edge_step(xhb, aS, i0, h, subo, adst, s, acc);
      edge_step(xhb, aS, i1, h, subo, adst, s, acc);
      edge_step(xhb, aS, i2, h, subo, adst, s, acc);
      edge_step(xhb, aS, i3, h, subo, adst, s, acc);
    }
  }

  const float inv = 1.f / s;           // per-head normalization
  #pragma unroll
  for (int k = 0; k < 8; ++k) acc[k] *= inv;

  // mean over this half's 8 heads (bits 2..4 of sublane; stays in half)
  #pragma unroll
  for (int msk = 4; msk <= 16; msk <<= 1) {
    #pragma unroll
    for (int k = 0; k < 8; ++k) acc[k] += __shfl_xor(acc[k], msk);
  }

  if (sub < 4 && valid) {              // sublane owns out channels sub*8..+7
    const float4* b4 = (const float4*)bias;
    const float4 bb0 = b4[sub * 2], bb1 = b4[sub * 2 + 1];
    float o8[8];
    o8[0] = acc[0] * 0.125f + bb0.x; o8[1] = acc[1] * 0.125f + bb0.y;
    o8[2] = acc[2] * 0.125f + bb0.z; o8[3] = acc[3] * 0.125f + bb0.w;
    o8[4] = acc[4] * 0.125f + bb1.x; o8[5] = acc[5] * 0.125f + bb1.y;
    o8[6] = acc[6] * 0.125f + bb1.z; o8[7] = acc[7] * 0.125f + bb1.w;
    if (RELU) {
      #pragma unroll
      for (int k = 0; k < 8; ++k) o8[k] = fmaxf(o8[k], 0.f);
    }
    if constexpr (sizeof(OUT_T) == 2) {   // fp16 output (h1)
      union { __half2 h2[4]; uint4 u; } pk;
      pk.h2[0] = __float22half2_rn(make_float2(o8[0], o8[1]));
      pk.h2[1] = __float22half2_rn(make_float2(o8[2], o8[3]));
      pk.h2[2] = __float22half2_rn(make_float2(o8[4], o8[5]));
      pk.h2[3] = __float22half2_rn(make_float2(o8[6], o8[7]));
      *(uint4*)((__half*)out + (size_t)node * 32 + sub * 8) = pk.u;
    } else {                               // fp32 output (z)
      float4 v0 = make_float4(o8[0], o8[1], o8[2], o8[3]);
      float4 v1 = make_float4(o8[4], o8[5], o8[6], o8[7]);
      float4* op = (float4*)((float*)out + (size_t)node * 32 + sub * 8);
      op[0] = v0; op[1] = v1;
    }
  }
}

// ================================ decoder ==================================
__global__ __launch_bounds__(256) void decode_kernel(
    const float* __restrict__ z, const int* __restrict__ eli,
    float* __restrict__ out, int el)
{
  const int t = blockIdx.x * blockDim.x + threadIdx.x;
  const int pair = t >> 3;
  const int sub  = t & 7;
  if (pair >= el) return;
  const uint32_t a = (uint32_t)eli[pair];
  const uint32_t b = (uint32_t)eli[el + pair];
  const float4* z4 = reinterpret_cast<const float4*>(z);
  const float4 va = z4[a * 8u + sub];
  const float4 vb = z4[b * 8u + sub];
  float dp = va.x * vb.x + va.y * vb.y + va.z * vb.z + va.w * vb.w;
  dp += __shfl_xor(dp, 1);
  dp += __shfl_xor(dp, 2);
  dp += __shfl_xor(dp, 4);
  if (sub == 0) out[pair] = dp;
}

// ================================ launcher =================================
extern "C" void kernel_launch(void* const* d_in, const int* in_sizes, int n_in,
                              void* d_out, int out_size, void* d_ws, size_t ws_size,
                              hipStream_t stream)
{
  const float* x   = (const float*)d_in[0];
  const int*   ei  = (const int*)  d_in[1];
  const int*   eli = (const int*)  d_in[2];
  const float* W1  = (const float*)d_in[3];
  const float* as1 = (const float*)d_in[4];
  const float* ad1 = (const float*)d_in[5];
  const float* b1  = (const float*)d_in[6];
  const float* W2  = (const float*)d_in[7];
  const float* as2 = (const float*)d_in[8];
  const float* ad2 = (const float*)d_in[9];
  const float* b2  = (const float*)d_in[10];
  float* out = (float*)d_out;

  const int n  = in_sizes[0] / 128;   // 50000
  const int e  = in_sizes[1] / 2;     // 400000
  const int el = in_sizes[2] / 2;     // 100000
  const int et = e + n;
  const int slots = et + 3 * n + 64;  // padded CSR capacity

  // workspace carve-up (16B-aligned chunks)
  char* p = (char*)d_ws;
  __half* xh       = (__half*)p;    p += (size_t)(n + 1) * 256 * 2; // +sentinel row
  float* aS        = (float*)p;     p += (size_t)(n + 1) * 8 * 4;   // +sentinel
  float* aD        = (float*)p;     p += (size_t)n * 8 * 4;
  int*   deg       = (int*)  p;     p += (size_t)((n + 3) & ~3) * 4;
  int*   off       = (int*)  p;     p += (size_t)(n + 4) * 4;       // off[n] used
  int*   cursor    = (int*)  p;     p += (size_t)n * 4;
  int*   part      = (int*)  p;     p += 128 * 4;
  int*   csr_src   = (int*)  p;     p += (size_t)slots * 4;
  __half* h1       = (__half*)p;    p += (size_t)n * 32 * 2;
  float* z         = (float*)p;     p += (size_t)n * 32 * 4;
  _Float16* W1p    = (_Float16*)p;  p += (size_t)16 * 272 * 8 * 2;
  _Float16* W2p    = (_Float16*)p;  p += (size_t)4 * 272 * 8 * 2;

  const int nblk = (n + 2047) / 2048;
  const int gblk = (n + 63) / 64;
  const int n4   = (n + 3) / 4;

  // CSR build + W packs
  zero_deg<<<(n4 + 255) / 256, 256, 0, stream>>>((uint4*)deg, n4);
  count_wtrans<<<20 + (et + 319) / 320, 320, 0, stream>>>(
      ei, deg, e, n, W1, as1, ad1, W1p, W2, as2, ad2, W2p);
  scan_part<<<nblk, 256, 0, stream>>>(deg, part, n);
  scan_fin<<<nblk, 256, 0, stream>>>(deg, part, off, cursor, csr_src, xh, aS, n);
  scatter_kernel<<<(et + 255) / 256, 256, 0, stream>>>(ei, cursor, csr_src, e, n);

  // layer 1
  mfma_gemm_att<128, false><<<gblk, 256, 0, stream>>>(x, W1p, xh, aS, aD, n);
  gat_gather<true, __half><<<(n + 3) / 4, 128, 0, stream>>>(
      xh, aS, aD, off, csr_src, b1, h1, n);
  // layer 2
  mfma_gemm_att<32, true><<<gblk, 256, 0, stream>>>(h1, W2p, xh, aS, aD, n);
  gat_gather<false, float><<<(n + 3) / 4, 128, 0, stream>>>(
      xh, aS, aD, off, csr_src, b2, z, n);
  // decoder
  decode_kernel<<<(el * 8 + 255) / 256, 256, 0, stream>>>(z, eli, out, el);
}